// Round 1
// 1062.616 us; speedup vs baseline: 1.2047x; 1.2047x over previous
//
#include <hip/hip_runtime.h>
#include <math.h>

// ---------------------------------------------------------------------------
// TransformerBlock: LN -> QKV -> MHA -> Wo(+resid) -> LN -> top1-MoE(+resid)
// R4: attention moved from fp32 VALU (374us, MfmaUtil=0) to 32x32x16 bf16
// MFMA with 3-pass hi/lo split precision (~2^-17 rel err, routing-safe).
// Swapped QK^T (S^T = K·Q^T) keeps softmax lane-local; PV computed as
// O^T = V^T·P with XOR-swizzled transposed-V LDS tiles; P-frags built
// in-register via cross-half shfl. T14 async staging (load next tile's
// K/V into regs during compute). GEMMs / MoE unchanged (R2/R3).
// ---------------------------------------------------------------------------

constexpr int NB = 4, NS = 1024, NHID = 1024, NHEAD = 16, HD = 64, NE = 8, NF = 4096;
constexpr int NT = NB * NS;          // 4096 tokens
constexpr float LN_EPS = 1e-5f;
constexpr size_t MiB = 1048576;

using bf16x8 = __attribute__((ext_vector_type(8))) short;
using f32x4  = __attribute__((ext_vector_type(4))) float;
using f32x16 = __attribute__((ext_vector_type(16))) float;
using u32x2  = __attribute__((ext_vector_type(2))) unsigned int;

__device__ __forceinline__ unsigned short f2bf(float x) {
    unsigned u = __float_as_uint(x);
    return (unsigned short)((u + 0x7fffu + ((u >> 16) & 1u)) >> 16);   // RNE
}
__device__ __forceinline__ float bf2f(unsigned short h) {
    return __uint_as_float((unsigned)h << 16);
}

__device__ __forceinline__ void gload_lds16(const void* g, void* l) {
    __builtin_amdgcn_global_load_lds(
        (const __attribute__((address_space(1))) void*)g,
        (__attribute__((address_space(3))) void*)l, 16, 0, 0);
}

// ---------------- LayerNorm ------------------------------------------------
// MODE 0: write hi+lo bf16 planes only (feeds bf16x3 GEMM)
// MODE 1: write fp32 (gate) + hi bf16 plane (feeds 1-pass MoE GEMM)
template<int MODE>
__global__ __launch_bounds__(256)
void ln_kernel(const float* __restrict__ x, const float* __restrict__ g,
               const float* __restrict__ b, float* __restrict__ y,
               unsigned short* __restrict__ yh, unsigned short* __restrict__ yl)
{
    const int t = blockIdx.x, tid = threadIdx.x;
    const float4 xv = ((const float4*)(x + (size_t)t * NHID))[tid];
    float s  = xv.x + xv.y + xv.z + xv.w;
    float sq = xv.x*xv.x + xv.y*xv.y + xv.z*xv.z + xv.w*xv.w;
    for (int off = 32; off > 0; off >>= 1) {
        s  += __shfl_down(s, off);
        sq += __shfl_down(sq, off);
    }
    __shared__ float ws_[4], wsq_[4], stats[2];
    const int wid = tid >> 6, lane = tid & 63;
    if (lane == 0) { ws_[wid] = s; wsq_[wid] = sq; }
    __syncthreads();
    if (tid == 0) {
        const float ts = ws_[0] + ws_[1] + ws_[2] + ws_[3];
        const float tq = wsq_[0] + wsq_[1] + wsq_[2] + wsq_[3];
        const float mu = ts * (1.0f / NHID);
        const float var = tq * (1.0f / NHID) - mu * mu;
        stats[0] = mu; stats[1] = rsqrtf(var + LN_EPS);
    }
    __syncthreads();
    const float mu = stats[0], rs = stats[1];
    const float4 gv = ((const float4*)g)[tid];
    const float4 bv = ((const float4*)b)[tid];
    float ov[4];
    ov[0] = (xv.x - mu) * rs * gv.x + bv.x;
    ov[1] = (xv.y - mu) * rs * gv.y + bv.y;
    ov[2] = (xv.z - mu) * rs * gv.z + bv.z;
    ov[3] = (xv.w - mu) * rs * gv.w + bv.w;
    if (MODE == 1) {
        float4 o4; o4.x = ov[0]; o4.y = ov[1]; o4.z = ov[2]; o4.w = ov[3];
        ((float4*)(y + (size_t)t * NHID))[tid] = o4;
    }
    unsigned long long ph = 0, pl = 0;
    #pragma unroll
    for (int j = 0; j < 4; ++j) {
        const unsigned short h = f2bf(ov[j]);
        ph |= (unsigned long long)h << (16 * j);
        if (MODE == 0) pl |= (unsigned long long)f2bf(ov[j] - bf2f(h)) << (16 * j);
    }
    ((unsigned long long*)(yh + (size_t)t * NHID))[tid] = ph;
    if (MODE == 0)
        ((unsigned long long*)(yl + (size_t)t * NHID))[tid] = pl;
}

// ---------------- Pack weight fp32 [K][N] -> bf16 [2][K/8][N][8] (hi,lo) ---
__global__ __launch_bounds__(256)
void pack_whl(const float* __restrict__ w, unsigned short* __restrict__ out,
              int K, int N)
{
    const int k8 = blockIdx.y;
    const int col = blockIdx.x * 256 + threadIdx.x;
    const float* src = w + (size_t)k8 * 8 * N + col;
    unsigned short th[8] __attribute__((aligned(16)));
    unsigned short tl[8] __attribute__((aligned(16)));
    #pragma unroll
    for (int j = 0; j < 8; ++j) {
        const float f = src[(size_t)j * N];
        th[j] = f2bf(f);
        tl[j] = f2bf(f - bf2f(th[j]));
    }
    const size_t plane = (size_t)(K / 8) * N * 8;
    const size_t o = ((size_t)k8 * N + col) * 8;
    *(f32x4*)(out + o)         = *(const f32x4*)th;
    *(f32x4*)(out + plane + o) = *(const f32x4*)tl;
}

// ---------------- Pack weight fp32 [E][K][N] -> bf16 [E][K/8][N][8] (hi) ---
__global__ __launch_bounds__(256)
void pack_w(const float* __restrict__ w, unsigned short* __restrict__ out,
            int K, int N)
{
    const int e = blockIdx.z, k8 = blockIdx.y;
    const int col = blockIdx.x * 256 + threadIdx.x;
    const float* src = w + ((size_t)e * K + (size_t)k8 * 8) * N + col;
    unsigned short tmp[8] __attribute__((aligned(16)));
    #pragma unroll
    for (int j = 0; j < 8; ++j) tmp[j] = f2bf(src[(size_t)j * N]);
    *(f32x4*)(out + (((size_t)e * (K / 8) + k8) * N + col) * 8) = *(const f32x4*)tmp;
}

// ---------------- bf16x3 MFMA GEMM: C = A @ W + bias (+resid) --------------
// A as hi/lo bf16 planes [M][K]; W packed [2][K/8][N][8] (hi,lo).
// BM=BN=128, BK=32, 256 thr (4 waves, 2x2). 3 MFMA passes: hh, hl, lh.
// QKV3: blockIdx.z selects weight z (stride 2*(K/8)*N*8), bias z, C + z*NT*N.
template<bool QKV3, bool RESID>
__global__ __launch_bounds__(256, 2)
void gemm3(const unsigned short* __restrict__ Ah, const unsigned short* __restrict__ Al,
           const unsigned short* __restrict__ Bp,
           const float* __restrict__ b0, const float* __restrict__ b1,
           const float* __restrict__ b2,
           const float* __restrict__ resid, float* __restrict__ C,
           int N, int K)
{
    __shared__ __attribute__((aligned(16))) unsigned short Ahs[4 * 128 * 8];
    __shared__ __attribute__((aligned(16))) unsigned short Als[4 * 128 * 8];
    __shared__ __attribute__((aligned(16))) unsigned short Bhs[4 * 128 * 8];
    __shared__ __attribute__((aligned(16))) unsigned short Bls[4 * 128 * 8];

    const int z  = QKV3 ? blockIdx.z : 0;
    const int m0 = blockIdx.y * 128;
    const int n0 = blockIdx.x * 128;
    const size_t plane = (size_t)(K / 8) * N * 8;
    const unsigned short* Bh = Bp + (size_t)z * 2 * plane;
    const unsigned short* Bl = Bh + plane;
    const float* bp = QKV3 ? (z == 0 ? b0 : z == 1 ? b1 : b2) : b0;
    float* Cp = C + (QKV3 ? (size_t)z * NT * N : 0);

    const int tid  = threadIdx.x;
    const int lane = tid & 63, wid = tid >> 6;
    const int quad = lane >> 4, l16 = lane & 15;
    const int wm = (wid >> 1) * 64;
    const int wn = (wid & 1) * 64;

    // staging: chunk c = q*128 + idx (16B per chunk), 512 chunks/plane, 2/thread
    const unsigned short *gAh[2], *gAl[2], *gBh[2], *gBl[2];
    void *lAh[2], *lAl[2], *lBh[2], *lBl[2];
    #pragma unroll
    for (int i = 0; i < 2; ++i) {
        const int c = tid + 256 * i;
        const int q = c >> 7, idx = c & 127;
        gAh[i] = Ah + (size_t)(m0 + idx) * K + q * 8;
        gAl[i] = Al + (size_t)(m0 + idx) * K + q * 8;
        gBh[i] = Bh + ((size_t)q * N + n0 + idx) * 8;
        gBl[i] = Bl + ((size_t)q * N + n0 + idx) * 8;
        lAh[i] = (void*)&Ahs[(size_t)c * 8];
        lAl[i] = (void*)&Als[(size_t)c * 8];
        lBh[i] = (void*)&Bhs[(size_t)c * 8];
        lBl[i] = (void*)&Bls[(size_t)c * 8];
    }

    f32x4 acc[4][4];
    #pragma unroll
    for (int mi = 0; mi < 4; ++mi)
        #pragma unroll
        for (int ni = 0; ni < 4; ++ni)
            acc[mi][ni] = (f32x4){0.f, 0.f, 0.f, 0.f};

    const size_t bstep = (size_t)4 * N * 8;
    for (int ks = 0; ks < K / 32; ++ks) {
        __syncthreads();
        #pragma unroll
        for (int i = 0; i < 2; ++i) {
            gload_lds16(gAh[i], lAh[i]);
            gload_lds16(gAl[i], lAl[i]);
            gload_lds16(gBh[i], lBh[i]);
            gload_lds16(gBl[i], lBl[i]);
            gAh[i] += 32; gAl[i] += 32; gBh[i] += bstep; gBl[i] += bstep;
        }
        __syncthreads();

        bf16x8 ah[4], al[4], bh[4], bl[4];
        #pragma unroll
        for (int mi = 0; mi < 4; ++mi) {
            ah[mi] = *(const bf16x8*)&Ahs[((size_t)quad * 128 + wm + mi * 16 + l16) * 8];
            al[mi] = *(const bf16x8*)&Als[((size_t)quad * 128 + wm + mi * 16 + l16) * 8];
        }
        #pragma unroll
        for (int ni = 0; ni < 4; ++ni) {
            bh[ni] = *(const bf16x8*)&Bhs[((size_t)quad * 128 + wn + ni * 16 + l16) * 8];
            bl[ni] = *(const bf16x8*)&Bls[((size_t)quad * 128 + wn + ni * 16 + l16) * 8];
        }
        #pragma unroll
        for (int mi = 0; mi < 4; ++mi)
            #pragma unroll
            for (int ni = 0; ni < 4; ++ni) {
                acc[mi][ni] = __builtin_amdgcn_mfma_f32_16x16x32_bf16(
                    ah[mi], bh[ni], acc[mi][ni], 0, 0, 0);
                acc[mi][ni] = __builtin_amdgcn_mfma_f32_16x16x32_bf16(
                    ah[mi], bl[ni], acc[mi][ni], 0, 0, 0);
                acc[mi][ni] = __builtin_amdgcn_mfma_f32_16x16x32_bf16(
                    al[mi], bh[ni], acc[mi][ni], 0, 0, 0);
            }
    }

    // epilogue: C/D layout col=l16, row=quad*4+reg
    #pragma unroll
    for (int mi = 0; mi < 4; ++mi) {
        const int rbase = wm + mi * 16 + quad * 4;
        #pragma unroll
        for (int r = 0; r < 4; ++r) {
            const size_t gm = m0 + rbase + r;
            #pragma unroll
            for (int ni = 0; ni < 4; ++ni) {
                const int col = n0 + wn + ni * 16 + l16;
                float vv = acc[mi][ni][r] + bp[col];
                if (RESID) vv += resid[gm * N + col];
                Cp[gm * N + col] = vv;
            }
        }
    }
}

// ---------------- MFMA flash attention (bf16x3 split precision) -------------
// Block: 128 q-rows, 4 waves x 32 q. Per kv-tile (64 rows):
//   S^T = K·Q^T via mfma_32x32x16 (3 passes Kh·Qh + Kh·Ql + Kl·Qh)
//   -> lane-local online softmax (q = lane&31)
//   -> P hi/lo frags built in-register (cross-half shfl_xor exchange)
//   -> O^T += V^T·P (3 passes Vh·Ph + Vh·Pl + Vl·Ph)
// K LDS: [doct][row][8] pad-520; V LDS: transposed [d][j] with octet XOR
// swizzle (j>>3)^(d&7) so PV ds_read_b128 avoids stride-128B conflicts.
// T14: next tile's K/V global loads issued before compute, written next iter.
__global__ __launch_bounds__(256, 2)
void attn_kernel(const float* __restrict__ q, const float* __restrict__ k,
                 const float* __restrict__ v,
                 unsigned short* __restrict__ oh, unsigned short* __restrict__ ol)
{
    struct KV {
        unsigned short Kp[2][4160];   // [plane][doct*520 + row*8 + (d&7)]
        unsigned short Vp[2][4096];   // [plane][d*64 + ((j>>3)^(d&7))*8 + (j&7)]
    };
    __shared__ union SMem { KV kv; float O[4 * 64 * 33]; } sm;
    __shared__ float linv[128];

    const int qt = blockIdx.x, hh = blockIdx.y, b = blockIdx.z;
    const int tid = threadIdx.x;
    const int lane = tid & 63, w = tid >> 6;
    const int l31 = lane & 31, hf = lane >> 5;

    const size_t rowbase = (size_t)b * NS;
    const size_t cb = (size_t)hh * HD;

    // ---- issue tile-0 K/V loads ------------------------------------------
    float4 kreg[4], vreg[2][2];
    auto loadKV = [&](int kt) {
        #pragma unroll
        for (int i = 0; i < 4; ++i) {
            const int c = tid + 256 * i, j = c >> 4, d4 = (c & 15) << 2;
            kreg[i] = *(const float4*)(k + (rowbase + kt * 64 + j) * NHID + cb + d4);
        }
        #pragma unroll
        for (int i = 0; i < 2; ++i) {
            const int c = tid + 256 * i;
            const int j2 = ((c >> 6) << 3) + (((c >> 4) & 3) << 1);
            const int d4 = (c & 15) << 2;
            vreg[i][0] = *(const float4*)(v + (rowbase + kt * 64 + j2) * NHID + cb + d4);
            vreg[i][1] = *(const float4*)(v + (rowbase + kt * 64 + j2 + 1) * NHID + cb + d4);
        }
    };
    loadKV(0);

    // ---- Q fragments in registers (hi/lo), 1/sqrt(D) folded ---------------
    // B-operand layout: lane holds Q[qb + l31][16s + 8hf + e]
    bf16x8 qfh[4], qfl[4];
    {
        const int qrow = qt * 128 + w * 32 + l31;
        const float* qp = q + (rowbase + qrow) * NHID + cb + hf * 8;
        #pragma unroll
        for (int s = 0; s < 4; ++s) {
            const float4 f0 = *(const float4*)(qp + s * 16);
            const float4 f1 = *(const float4*)(qp + s * 16 + 4);
            const float ff[8] = {f0.x, f0.y, f0.z, f0.w, f1.x, f1.y, f1.z, f1.w};
            #pragma unroll
            for (int e = 0; e < 8; ++e) {
                const float sv = ff[e] * 0.125f;
                const unsigned short hv = f2bf(sv);
                qfh[s][e] = (short)hv;
                qfl[s][e] = (short)f2bf(sv - bf2f(hv));
            }
        }
    }

    f32x16 oa[2];
    #pragma unroll
    for (int mfd = 0; mfd < 2; ++mfd)
        #pragma unroll
        for (int r = 0; r < 16; ++r) oa[mfd][r] = 0.f;
    float m_run = -1e30f, l_run = 0.f;

    for (int kt = 0; kt < NS / 64; ++kt) {
        __syncthreads();   // previous tile's LDS reads done

        // ---- write staged K (hi/lo, gemm layout, pad 520) -----------------
        #pragma unroll
        for (int i = 0; i < 4; ++i) {
            const int c = tid + 256 * i, j = c >> 4, d4 = (c & 15) << 2;
            const float* f = (const float*)&kreg[i];
            unsigned short hs[4], ls[4];
            #pragma unroll
            for (int e = 0; e < 4; ++e) {
                hs[e] = f2bf(f[e]); ls[e] = f2bf(f[e] - bf2f(hs[e]));
            }
            u32x2 wh, wl;
            wh[0] = hs[0] | ((unsigned)hs[1] << 16); wh[1] = hs[2] | ((unsigned)hs[3] << 16);
            wl[0] = ls[0] | ((unsigned)ls[1] << 16); wl[1] = ls[2] | ((unsigned)ls[3] << 16);
            const int ad = (d4 >> 3) * 520 + j * 8 + (d4 & 7);
            *(u32x2*)&sm.kv.Kp[0][ad] = wh;
            *(u32x2*)&sm.kv.Kp[1][ad] = wl;
        }
        // ---- write staged V (transposed + octet swizzle, hi/lo) -----------
        #pragma unroll
        for (int i = 0; i < 2; ++i) {
            const int c = tid + 256 * i;
            const int j2 = ((c >> 6) << 3) + (((c >> 4) & 3) << 1);
            const int d4 = (c & 15) << 2;
            const float* fa = (const float*)&vreg[i][0];
            const float* fb = (const float*)&vreg[i][1];
            #pragma unroll
            for (int dd = 0; dd < 4; ++dd) {
                const int d = d4 + dd;
                const unsigned short ah_ = f2bf(fa[dd]), bh_ = f2bf(fb[dd]);
                const unsigned short al_ = f2bf(fa[dd] - bf2f(ah_));
                const unsigned short bl_ = f2bf(fb[dd] - bf2f(bh_));
                const int ad = d * 64 + (((j2 >> 3) ^ (d & 7)) << 3) + (j2 & 7);
                *(unsigned*)&sm.kv.Vp[0][ad] = ah_ | ((unsigned)bh_ << 16);
                *(unsigned*)&sm.kv.Vp[1][ad] = al_ | ((unsigned)bl_ << 16);
            }
        }
        if (kt + 1 < NS / 64) loadKV(kt + 1);   // T14: hide HBM under compute
        __syncthreads();   // LDS ready

        // ---- S^T = K·Q^T, 3 passes ---------------------------------------
        f32x16 sa[2];
        #pragma unroll
        for (int mf = 0; mf < 2; ++mf)
            #pragma unroll
            for (int r = 0; r < 16; ++r) sa[mf][r] = 0.f;
        #pragma unroll
        for (int mf = 0; mf < 2; ++mf) {
            bf16x8 kf[4];
            #pragma unroll
            for (int s = 0; s < 4; ++s)
                kf[s] = *(const bf16x8*)&sm.kv.Kp[0][(2*s+hf)*520 + (mf*32+l31)*8];
            #pragma unroll
            for (int s = 0; s < 4; ++s)
                sa[mf] = __builtin_amdgcn_mfma_f32_32x32x16_bf16(kf[s], qfh[s], sa[mf], 0, 0, 0);
            #pragma unroll
            for (int s = 0; s < 4; ++s)
                sa[mf] = __builtin_amdgcn_mfma_f32_32x32x16_bf16(kf[s], qfl[s], sa[mf], 0, 0, 0);
            #pragma unroll
            for (int s = 0; s < 4; ++s)
                kf[s] = *(const bf16x8*)&sm.kv.Kp[1][(2*s+hf)*520 + (mf*32+l31)*8];
            #pragma unroll
            for (int s = 0; s < 4; ++s)
                sa[mf] = __builtin_amdgcn_mfma_f32_32x32x16_bf16(kf[s], qfh[s], sa[mf], 0, 0, 0);
        }

        // ---- online softmax: lane owns row q = qb + l31 -------------------
        float tm = sa[0][0];
        #pragma unroll
        for (int r = 1; r < 16; ++r) tm = fmaxf(tm, sa[0][r]);
        #pragma unroll
        for (int r = 0; r < 16; ++r) tm = fmaxf(tm, sa[1][r]);
        tm = fmaxf(tm, __shfl_xor(tm, 32));
        const float newm = fmaxf(m_run, tm);
        const float al = __expf(m_run - newm);
        m_run = newm;
        float ps = 0.f;
        #pragma unroll
        for (int mf = 0; mf < 2; ++mf)
            #pragma unroll
            for (int r = 0; r < 16; ++r) {
                const float pv = __expf(sa[mf][r] - newm);
                sa[mf][r] = pv; ps += pv;
            }
        ps += __shfl_xor(ps, 32);
        l_run = l_run * al + ps;
        #pragma unroll
        for (int mfd = 0; mfd < 2; ++mfd)
            #pragma unroll
            for (int r = 0; r < 16; ++r) oa[mfd][r] *= al;

        // ---- P fragments (hi/lo) via cross-half exchange ------------------
        // frag for j-step t: lane element e <-> j = 16t + 8hf + e
        bf16x8 pfh[4], pfl[4];
        #pragma unroll
        for (int t = 0; t < 4; ++t) {
            const int mfp = t >> 1, u8 = (t & 1) * 8;
            unsigned short hb[8]; float lo8[8];
            #pragma unroll
            for (int e = 0; e < 8; ++e) {
                const float pv = sa[mfp][u8 + e];
                hb[e] = f2bf(pv); lo8[e] = pv - bf2f(hb[e]);
            }
            {
                const unsigned X0 = hb[0] | ((unsigned)hb[1] << 16);
                const unsigned X1 = hb[2] | ((unsigned)hb[3] << 16);
                const unsigned X2 = hb[4] | ((unsigned)hb[5] << 16);
                const unsigned X3 = hb[6] | ((unsigned)hb[7] << 16);
                const unsigned s0 = (unsigned)__shfl_xor((int)X0, 32);
                const unsigned s1 = (unsigned)__shfl_xor((int)X1, 32);
                const unsigned s2 = (unsigned)__shfl_xor((int)X2, 32);
                const unsigned s3 = (unsigned)__shfl_xor((int)X3, 32);
                union UU { unsigned wd[4]; bf16x8 vv; } uu;
                uu.wd[0] = hf ? s2 : X0;
                uu.wd[1] = hf ? s3 : X1;
                uu.wd[2] = hf ? X2 : s0;
                uu.wd[3] = hf ? X3 : s1;
                pfh[t] = uu.vv;
            }
            {
                unsigned short lb[8];
                #pragma unroll
                for (int e = 0; e < 8; ++e) lb[e] = f2bf(lo8[e]);
                const unsigned Y0 = lb[0] | ((unsigned)lb[1] << 16);
                const unsigned Y1 = lb[2] | ((unsigned)lb[3] << 16);
                const unsigned Y2 = lb[4] | ((unsigned)lb[5] << 16);
                const unsigned Y3 = lb[6] | ((unsigned)lb[7] << 16);
                const unsigned s0 = (unsigned)__shfl_xor((int)Y0, 32);
                const unsigned s1 = (unsigned)__shfl_xor((int)Y1, 32);
                const unsigned s2 = (unsigned)__shfl_xor((int)Y2, 32);
                const unsigned s3 = (unsigned)__shfl_xor((int)Y3, 32);
                union UU { unsigned wd[4]; bf16x8 vv; } uu;
                uu.wd[0] = hf ? s2 : Y0;
                uu.wd[1] = hf ? s3 : Y1;
                uu.wd[2] = hf ? Y2 : s0;
                uu.wd[3] = hf ? Y3 : s1;
                pfl[t] = uu.vv;
            }
        }

        // ---- O^T += V^T·P, 3 passes --------------------------------------
        #pragma unroll
        for (int mfd = 0; mfd < 2; ++mfd) {
            const int db = (mfd * 32 + l31) * 64;
            const int sw = l31 & 7;           // d&7 for this lane
            bf16x8 vf[4];
            #pragma unroll
            for (int ks = 0; ks < 4; ++ks)
                vf[ks] = *(const bf16x8*)&sm.kv.Vp[0][db + (((2*ks+hf) ^ sw) << 3)];
            #pragma unroll
            for (int ks = 0; ks < 4; ++ks)
                oa[mfd] = __builtin_amdgcn_mfma_f32_32x32x16_bf16(vf[ks], pfh[ks], oa[mfd], 0, 0, 0);
            #pragma unroll
            for (int ks = 0; ks < 4; ++ks)
                oa[mfd] = __builtin_amdgcn_mfma_f32_32x32x16_bf16(vf[ks], pfl[ks], oa[mfd], 0, 0, 0);
            #pragma unroll
            for (int ks = 0; ks < 4; ++ks)
                vf[ks] = *(const bf16x8*)&sm.kv.Vp[1][db + (((2*ks+hf) ^ sw) << 3)];
            #pragma unroll
            for (int ks = 0; ks < 4; ++ks)
                oa[mfd] = __builtin_amdgcn_mfma_f32_32x32x16_bf16(vf[ks], pfh[ks], oa[mfd], 0, 0, 0);
        }
    }

    // ---- epilogue: O^T -> padded LDS -> normalized hi/lo bf16 stores ------
    __syncthreads();   // done reading K/V LDS; overlay with O
    {
        float* Ow = sm.O + w * (64 * 33);
        #pragma unroll
        for (int mfd = 0; mfd < 2; ++mfd)
            #pragma unroll
            for (int r = 0; r < 16; ++r) {
                const int dr = mfd * 32 + (r & 3) + 8 * (r >> 2) + 4 * hf;
                Ow[dr * 33 + l31] = oa[mfd][r];
            }
        if (hf == 0) linv[w * 32 + l31] = 1.0f / l_run;
    }
    __syncthreads();
    #pragma unroll
    for (int it = 0; it < 8; ++it) {
        const int c = tid + 256 * it;
        const int qq = c >> 4, d4 = (c & 15) << 2;
        const float* Or = sm.O + (qq >> 5) * (64 * 33) + (qq & 31);
        const float sc_ = linv[qq];
        unsigned short hs[4], ls[4];
        #pragma unroll
        for (int e = 0; e < 4; ++e) {
            const float vv = Or[(d4 + e) * 33] * sc_;
            hs[e] = f2bf(vv); ls[e] = f2bf(vv - bf2f(hs[e]));
        }
        u32x2 ph_, pl_;
        ph_[0] = hs[0] | ((unsigned)hs[1] << 16); ph_[1] = hs[2] | ((unsigned)hs[3] << 16);
        pl_[0] = ls[0] | ((unsigned)ls[1] << 16); pl_[1] = ls[2] | ((unsigned)ls[3] << 16);
        const size_t o = (rowbase + qt * 128 + qq) * NHID + cb + d4;
        *(u32x2*)&oh[o] = ph_;
        *(u32x2*)&ol[o] = pl_;
    }
}

// ---------------- Gate: fp32 logits, argmax (first-max), token scatter ------
__global__ __launch_bounds__(64)
void gate_kernel(const float* __restrict__ hn2, const float* __restrict__ gw,
                 const float* __restrict__ gb, int* __restrict__ counts,
                 int* __restrict__ tok)
{
    const int t = blockIdx.x, lane = threadIdx.x;
    const float* row = hn2 + (size_t)t * NHID;
    float acc[NE] = {};
    for (int hh = lane; hh < NHID; hh += 64) {
        const float xv = row[hh];
        const float4 g0 = ((const float4*)(gw + (size_t)hh * NE))[0];
        const float4 g1 = ((const float4*)(gw + (size_t)hh * NE))[1];
        acc[0] += xv * g0.x; acc[1] += xv * g0.y; acc[2] += xv * g0.z; acc[3] += xv * g0.w;
        acc[4] += xv * g1.x; acc[5] += xv * g1.y; acc[6] += xv * g1.z; acc[7] += xv * g1.w;
    }
    #pragma unroll
    for (int e = 0; e < NE; ++e)
        for (int off = 32; off > 0; off >>= 1)
            acc[e] += __shfl_down(acc[e], off);
    if (lane == 0) {
        float best = -1e30f; int bi = 0;
        #pragma unroll
        for (int e = 0; e < NE; ++e) {
            const float lv = acc[e] + gb[e];
            if (lv > best) { best = lv; bi = e; }   // strict >: first-max (jnp.argmax)
        }
        const int pos = atomicAdd(&counts[bi], 1);
        tok[(size_t)bi * NT + pos] = t;
    }
}

// ---------------- MoE expert GEMM, 1-pass bf16 MFMA (unchanged from R2) -----
template<int BN, bool BF16OUT>
__global__ __launch_bounds__(256, 2)
void moe_mfma(const unsigned short* __restrict__ A,   // bf16 [NT][K]
              const unsigned short* __restrict__ Bp,  // bf16 packed [E][K/8][N][8]
              const float* __restrict__ bias,         // [E][N]
              const float* __restrict__ resid,        // [NT][N] or null
              void* __restrict__ Cout,                // bf16 or fp32 [NT][N]
              int N, int K,
              const int* __restrict__ rows, const int* __restrict__ counts)
{
    constexpr int NI = BN / 32;
    constexpr int NBCH = (4 * BN) / 256;
    __shared__ __attribute__((aligned(16))) unsigned short As[4 * 128 * 8];
    __shared__ __attribute__((aligned(16))) unsigned short Bs[4 * BN * 8];

    const int e = blockIdx.z;
    const int Meff = counts[e];
    const int m0 = blockIdx.y * 128;
    if (m0 >= Meff) return;
    const int n0 = blockIdx.x * BN;
    const int* rl = rows + (size_t)e * NT;

    const int tid  = threadIdx.x;
    const int lane = tid & 63, wid = tid >> 6;
    const int quad = lane >> 4, l16 = lane & 15;
    const int wm = (wid >> 1) * 64;
    const int wn = (wid & 1) * (BN / 2);

    const unsigned short* gA[2]; void* lA[2];
    #pragma unroll
    for (int i = 0; i < 2; ++i) {
        const int c = tid + 256 * i;
        const int q = c >> 7, row = c & 127;
        int m = m0 + row; if (m >= Meff) m = Meff - 1;
        gA[i] = A + (size_t)rl[m] * K + q * 8;
        lA[i] = (void*)&As[(size_t)c * 8];
    }
    const unsigned short* gB[NBCH]; void* lB[NBCH];
    #pragma unroll
    for (int i = 0; i < NBCH; ++i) {
        const int c = tid + 256 * i;
        const int q = c / BN, n = c % BN;
        gB[i] = Bp + (((size_t)e * (K / 8) + q) * N + n0 + n) * 8;
        lB[i] = (void*)&Bs[(size_t)c * 8];
    }

    f32x4 acc[4][NI];
    #pragma unroll
    for (int mi = 0; mi < 4; ++mi)
        #pragma unroll
        for (int ni = 0; ni < NI; ++ni)
            acc[mi][ni] = (f32x4){0.f, 0.f, 0.f, 0.f};

    const size_t bstep = (size_t)4 * N * 8;
    for (int ks = 0; ks < K / 32; ++ks) {
        __syncthreads();
        gload_lds16(gA[0], lA[0]);
        gload_lds16(gA[1], lA[1]);
        #pragma unroll
        for (int i = 0; i < NBCH; ++i) gload_lds16(gB[i], lB[i]);
        gA[0] += 32; gA[1] += 32;
        #pragma unroll
        for (int i = 0; i < NBCH; ++i) gB[i] += bstep;
        __syncthreads();

        bf16x8 af[4], bfr[NI];
        #pragma unroll
        for (int mi = 0; mi < 4; ++mi)
            af[mi] = *(const bf16x8*)&As[((size_t)quad * 128 + wm + mi * 16 + l16) * 8];
        #pragma unroll
        for (int ni = 0; ni < NI; ++ni)
            bfr[ni] = *(const bf16x8*)&Bs[((size_t)quad * BN + wn + ni * 16 + l16) * 8];
        #pragma unroll
        for (int mi = 0; mi < 4; ++mi)
            #pragma unroll
            for (int ni = 0; ni < NI; ++ni)
                acc[mi][ni] = __builtin_amdgcn_mfma_f32_16x16x32_bf16(
                    af[mi], bfr[ni], acc[mi][ni], 0, 0, 0);
    }

    #pragma unroll
    for (int mi = 0; mi < 4; ++mi) {
        const int rbase = wm + mi * 16 + quad * 4;
        #pragma unroll
        for (int r = 0; r < 4; ++r) {
            const int m = m0 + rbase + r;
            if (m >= Meff) continue;
            const int gr = rl[m];
            #pragma unroll
            for (int ni = 0; ni < NI; ++ni) {
                const int col = n0 + wn + ni * 16 + l16;
                float vv = acc[mi][ni][r] + bias[(size_t)e * N + col];
                if (BF16OUT) {
                    vv = fmaxf(vv, 0.f);
                    ((unsigned short*)Cout)[(size_t)gr * N + col] = f2bf(vv);
                } else {
                    vv += resid[(size_t)gr * N + col];
                    ((float*)Cout)[(size_t)gr * N + col] = vv;
                }
            }
        }
    }
}

// ---------------------------------------------------------------------------
extern "C" void kernel_launch(void* const* d_in, const int* in_sizes, int n_in,
                              void* d_out, int out_size, void* d_ws, size_t ws_size,
                              hipStream_t stream)
{
    (void)in_sizes; (void)n_in; (void)out_size; (void)ws_size;
    const float* x      = (const float*)d_in[0];
    const float* ln1_g  = (const float*)d_in[1];
    const float* ln1_b  = (const float*)d_in[2];
    const float* ln2_g  = (const float*)d_in[3];
    const float* ln2_b  = (const float*)d_in[4];
    const float* wq     = (const float*)d_in[5];
    const float* bq     = (const float*)d_in[6];
    const float* wk     = (const float*)d_in[7];
    const float* bk     = (const float*)d_in[8];
    const float* wv     = (const float*)d_in[9];
    const float* bv     = (const float*)d_in[10];
    const float* wo     = (const float*)d_in[11];
    const float* bo     = (const float*)d_in[12];
    const float* gate_w = (const float*)d_in[13];
    const float* gate_b = (const float*)d_in[14];
    const float* w1     = (const float*)d_in[15];
    const float* b1     = (const float*)d_in[16];
    const float* w2     = (const float*)d_in[17];
    const float* b2     = (const float*)d_in[18];
    float* out = (float*)d_out;

    // workspace layout (128 MiB total; R1 proved 128.13 MiB ok):
    //  0-16   q        -> (after Wo) MoE wpack [0,64)
    //  16-32  k
    //  32-48  v
    //  48-56  hnh      -> (after QKV) oh
    //  56-64  hnl      -> ol
    //  64-76  qkv weight packs (hi+lo, 4 MiB each) -> (after Wo) hn2bf 64-72
    //  72-76  (dead wv pack) -> tok (128 KB) + cnts
    //  76-80  wo pack
    //  80-96  x2 (alive to end)
    //  96-112 hn2f     -> (after gate) mid low half
    //  96-128 mid bf16 [NT][NF]
    char* W8 = (char*)d_ws;
    float*          qbuf   = (float*)(W8);
    float*          kbuf   = (float*)(W8 + 16 * MiB);
    float*          vbuf   = (float*)(W8 + 32 * MiB);
    unsigned short* hnh    = (unsigned short*)(W8 + 48 * MiB);
    unsigned short* hnl    = (unsigned short*)(W8 + 56 * MiB);
    unsigned short* ohb    = (unsigned short*)(W8 + 48 * MiB);
    unsigned short* olb    = (unsigned short*)(W8 + 56 * MiB);
    unsigned short* qkvpk  = (unsigned short*)(W8 + 64 * MiB);   // [3][2][128][1024][8]
    unsigned short* wopk   = (unsigned short*)(W8 + 76 * MiB);
    unsigned short* hn2bf  = (unsigned short*)(W8 + 64 * MiB);
    int*            tok    = (int*)(W8 + 72 * MiB);
    int*            cnts   = (int*)(W8 + 72 * MiB + (size_t)NE * NT * 4);
    float*          x2buf  = (float*)(W8 + 80 * MiB);
    float*          hn2f   = (float*)(W8 + 96 * MiB);
    unsigned short* mid    = (unsigned short*)(W8 + 96 * MiB);
    unsigned short* wpack  = (unsigned short*)(W8);              // MoE, 64 MiB

    const size_t wsz = (size_t)2 * NHID * NHID;   // elems per packed weight (hi+lo)

    // 0. pack QKV + Wo weights -> hi/lo bf16 planes
    {
        dim3 g(NHID / 256, NHID / 8, 1);
        pack_whl<<<g, 256, 0, stream>>>(wq, qkvpk,           NHID, NHID);
        pack_whl<<<g, 256, 0, stream>>>(wk, qkvpk + wsz,     NHID, NHID);
        pack_whl<<<g, 256, 0, stream>>>(wv, qkvpk + 2 * wsz, NHID, NHID);
        pack_whl<<<g, 256, 0, stream>>>(wo, wopk,            NHID, NHID);
    }

    // 1. LN1(x) -> hi/lo planes
    ln_kernel<0><<<NT, 256, 0, stream>>>(x, ln1_g, ln1_b, nullptr, hnh, hnl);

    // 2. q,k,v = hn @ {wq,wk,wv} + bias   (bf16x3 MFMA, fused over z)
    {
        dim3 g(NHID / 128, NT / 128, 3);
        gemm3<true, false><<<g, 256, 0, stream>>>(
            hnh, hnl, qkvpk, bq, bk, bv, nullptr, qbuf, NHID, NHID);
    }

    // 3. o = attention(q,k,v) -> hi/lo planes (overwrites hnh/hnl)
    {
        dim3 g(NS / 128, NHEAD, NB);
        attn_kernel<<<g, 256, 0, stream>>>(qbuf, kbuf, vbuf, ohb, olb);
    }

    // 4. x2 = x + o @ wo + bo   (bf16x3 MFMA)
    {
        dim3 g(NHID / 128, NT / 128, 1);
        gemm3<false, true><<<g, 256, 0, stream>>>(
            ohb, olb, wopk, bo, nullptr, nullptr, x, x2buf, NHID, NHID);
    }

    // 5. hn2 = LN2(x2) -> fp32 (gate) + bf16 hi (MoE A)
    ln_kernel<1><<<NT, 256, 0, stream>>>(x2buf, ln2_g, ln2_b, hn2f, hn2bf, nullptr);

    // 6. top-1 routing (fp32)
    hipMemsetAsync(cnts, 0, NE * sizeof(int), stream);
    gate_kernel<<<NT, 64, 0, stream>>>(hn2f, gate_w, gate_b, cnts, tok);

    // 7. pack w1 (hi only) -> wpack (overwrites q/k/v/oh/ol; all dead)
    {
        dim3 g(NF / 256, NHID / 8, NE);
        pack_w<<<g, 256, 0, stream>>>(w1, wpack, NHID, NF);
    }
    // 8. mid = relu(gather(hn2bf) @ w1[e] + b1[e])  (bf16 out; overlays hn2f)
    {
        dim3 g(NF / 128, NT / 128, NE);
        moe_mfma<128, true><<<g, 256, 0, stream>>>(
            hn2bf, wpack, b1, nullptr, mid, NF, NHID, tok, cnts);
    }
    // 9. pack w2 (GEMM1 done with w1 pack)
    {
        dim3 g(NHID / 256, NF / 8, NE);
        pack_w<<<g, 256, 0, stream>>>(w2, wpack, NF, NHID);
    }
    // 10. out = x2 + gather(mid) @ w2[e] + b2[e]
    {
        dim3 g(NHID / 64, NT / 128, NE);
        moe_mfma<64, false><<<g, 256, 0, stream>>>(
            mid, wpack, b2, x2buf, out, NHID, NF, tok, cnts);
    }
}

// Round 2
// 922.641 us; speedup vs baseline: 1.3874x; 1.1517x over previous
//
#include <hip/hip_runtime.h>
#include <math.h>

// ---------------------------------------------------------------------------
// TransformerBlock: LN -> QKV -> MHA -> Wo(+resid) -> LN -> top1-MoE(+resid)
// R5: MoE GEMMs rewritten as compact grouped-GEMM. Old scheme: 8192-block
// grid w/ early exit -> 12.6% occupancy, weights fetched 4x (242MB @ 793GB/s
// = the whole 340us). New: m-loop inside block (weights streamed ~1x, L2
// dedupes), expert->XCD pinning (e = blockIdx%8) for A/W panel L2 reuse,
// 1-barrier double-buffered k-loop (stage k+1 || compute k). Attention (R4
// MFMA bf16x3) and dense GEMMs (R3) unchanged.
// ---------------------------------------------------------------------------

constexpr int NB = 4, NS = 1024, NHID = 1024, NHEAD = 16, HD = 64, NE = 8, NF = 4096;
constexpr int NT = NB * NS;          // 4096 tokens
constexpr float LN_EPS = 1e-5f;
constexpr size_t MiB = 1048576;

using bf16x8 = __attribute__((ext_vector_type(8))) short;
using f32x4  = __attribute__((ext_vector_type(4))) float;
using f32x16 = __attribute__((ext_vector_type(16))) float;
using u32x2  = __attribute__((ext_vector_type(2))) unsigned int;

__device__ __forceinline__ unsigned short f2bf(float x) {
    unsigned u = __float_as_uint(x);
    return (unsigned short)((u + 0x7fffu + ((u >> 16) & 1u)) >> 16);   // RNE
}
__device__ __forceinline__ float bf2f(unsigned short h) {
    return __uint_as_float((unsigned)h << 16);
}

__device__ __forceinline__ void gload_lds16(const void* g, void* l) {
    __builtin_amdgcn_global_load_lds(
        (const __attribute__((address_space(1))) void*)g,
        (__attribute__((address_space(3))) void*)l, 16, 0, 0);
}

// ---------------- LayerNorm ------------------------------------------------
// MODE 0: write hi+lo bf16 planes only (feeds bf16x3 GEMM)
// MODE 1: write fp32 (gate) + hi bf16 plane (feeds 1-pass MoE GEMM)
template<int MODE>
__global__ __launch_bounds__(256)
void ln_kernel(const float* __restrict__ x, const float* __restrict__ g,
               const float* __restrict__ b, float* __restrict__ y,
               unsigned short* __restrict__ yh, unsigned short* __restrict__ yl)
{
    const int t = blockIdx.x, tid = threadIdx.x;
    const float4 xv = ((const float4*)(x + (size_t)t * NHID))[tid];
    float s  = xv.x + xv.y + xv.z + xv.w;
    float sq = xv.x*xv.x + xv.y*xv.y + xv.z*xv.z + xv.w*xv.w;
    for (int off = 32; off > 0; off >>= 1) {
        s  += __shfl_down(s, off);
        sq += __shfl_down(sq, off);
    }
    __shared__ float ws_[4], wsq_[4], stats[2];
    const int wid = tid >> 6, lane = tid & 63;
    if (lane == 0) { ws_[wid] = s; wsq_[wid] = sq; }
    __syncthreads();
    if (tid == 0) {
        const float ts = ws_[0] + ws_[1] + ws_[2] + ws_[3];
        const float tq = wsq_[0] + wsq_[1] + wsq_[2] + wsq_[3];
        const float mu = ts * (1.0f / NHID);
        const float var = tq * (1.0f / NHID) - mu * mu;
        stats[0] = mu; stats[1] = rsqrtf(var + LN_EPS);
    }
    __syncthreads();
    const float mu = stats[0], rs = stats[1];
    const float4 gv = ((const float4*)g)[tid];
    const float4 bv = ((const float4*)b)[tid];
    float ov[4];
    ov[0] = (xv.x - mu) * rs * gv.x + bv.x;
    ov[1] = (xv.y - mu) * rs * gv.y + bv.y;
    ov[2] = (xv.z - mu) * rs * gv.z + bv.z;
    ov[3] = (xv.w - mu) * rs * gv.w + bv.w;
    if (MODE == 1) {
        float4 o4; o4.x = ov[0]; o4.y = ov[1]; o4.z = ov[2]; o4.w = ov[3];
        ((float4*)(y + (size_t)t * NHID))[tid] = o4;
    }
    unsigned long long ph = 0, pl = 0;
    #pragma unroll
    for (int j = 0; j < 4; ++j) {
        const unsigned short h = f2bf(ov[j]);
        ph |= (unsigned long long)h << (16 * j);
        if (MODE == 0) pl |= (unsigned long long)f2bf(ov[j] - bf2f(h)) << (16 * j);
    }
    ((unsigned long long*)(yh + (size_t)t * NHID))[tid] = ph;
    if (MODE == 0)
        ((unsigned long long*)(yl + (size_t)t * NHID))[tid] = pl;
}

// ---------------- Pack weight fp32 [K][N] -> bf16 [2][K/8][N][8] (hi,lo) ---
__global__ __launch_bounds__(256)
void pack_whl(const float* __restrict__ w, unsigned short* __restrict__ out,
              int K, int N)
{
    const int k8 = blockIdx.y;
    const int col = blockIdx.x * 256 + threadIdx.x;
    const float* src = w + (size_t)k8 * 8 * N + col;
    unsigned short th[8] __attribute__((aligned(16)));
    unsigned short tl[8] __attribute__((aligned(16)));
    #pragma unroll
    for (int j = 0; j < 8; ++j) {
        const float f = src[(size_t)j * N];
        th[j] = f2bf(f);
        tl[j] = f2bf(f - bf2f(th[j]));
    }
    const size_t plane = (size_t)(K / 8) * N * 8;
    const size_t o = ((size_t)k8 * N + col) * 8;
    *(f32x4*)(out + o)         = *(const f32x4*)th;
    *(f32x4*)(out + plane + o) = *(const f32x4*)tl;
}

// ---------------- Pack weight fp32 [E][K][N] -> bf16 [E][K/8][N][8] (hi) ---
__global__ __launch_bounds__(256)
void pack_w(const float* __restrict__ w, unsigned short* __restrict__ out,
            int K, int N)
{
    const int e = blockIdx.z, k8 = blockIdx.y;
    const int col = blockIdx.x * 256 + threadIdx.x;
    const float* src = w + ((size_t)e * K + (size_t)k8 * 8) * N + col;
    unsigned short tmp[8] __attribute__((aligned(16)));
    #pragma unroll
    for (int j = 0; j < 8; ++j) tmp[j] = f2bf(src[(size_t)j * N]);
    *(f32x4*)(out + (((size_t)e * (K / 8) + k8) * N + col) * 8) = *(const f32x4*)tmp;
}

// ---------------- bf16x3 MFMA GEMM: C = A @ W + bias (+resid) --------------
// A as hi/lo bf16 planes [M][K]; W packed [2][K/8][N][8] (hi,lo).
// BM=BN=128, BK=32, 256 thr (4 waves, 2x2). 3 MFMA passes: hh, hl, lh.
// QKV3: blockIdx.z selects weight z (stride 2*(K/8)*N*8), bias z, C + z*NT*N.
template<bool QKV3, bool RESID>
__global__ __launch_bounds__(256, 2)
void gemm3(const unsigned short* __restrict__ Ah, const unsigned short* __restrict__ Al,
           const unsigned short* __restrict__ Bp,
           const float* __restrict__ b0, const float* __restrict__ b1,
           const float* __restrict__ b2,
           const float* __restrict__ resid, float* __restrict__ C,
           int N, int K)
{
    __shared__ __attribute__((aligned(16))) unsigned short Ahs[4 * 128 * 8];
    __shared__ __attribute__((aligned(16))) unsigned short Als[4 * 128 * 8];
    __shared__ __attribute__((aligned(16))) unsigned short Bhs[4 * 128 * 8];
    __shared__ __attribute__((aligned(16))) unsigned short Bls[4 * 128 * 8];

    const int z  = QKV3 ? blockIdx.z : 0;
    const int m0 = blockIdx.y * 128;
    const int n0 = blockIdx.x * 128;
    const size_t plane = (size_t)(K / 8) * N * 8;
    const unsigned short* Bh = Bp + (size_t)z * 2 * plane;
    const unsigned short* Bl = Bh + plane;
    const float* bp = QKV3 ? (z == 0 ? b0 : z == 1 ? b1 : b2) : b0;
    float* Cp = C + (QKV3 ? (size_t)z * NT * N : 0);

    const int tid  = threadIdx.x;
    const int lane = tid & 63, wid = tid >> 6;
    const int quad = lane >> 4, l16 = lane & 15;
    const int wm = (wid >> 1) * 64;
    const int wn = (wid & 1) * 64;

    // staging: chunk c = q*128 + idx (16B per chunk), 512 chunks/plane, 2/thread
    const unsigned short *gAh[2], *gAl[2], *gBh[2], *gBl[2];
    void *lAh[2], *lAl[2], *lBh[2], *lBl[2];
    #pragma unroll
    for (int i = 0; i < 2; ++i) {
        const int c = tid + 256 * i;
        const int q = c >> 7, idx = c & 127;
        gAh[i] = Ah + (size_t)(m0 + idx) * K + q * 8;
        gAl[i] = Al + (size_t)(m0 + idx) * K + q * 8;
        gBh[i] = Bh + ((size_t)q * N + n0 + idx) * 8;
        gBl[i] = Bl + ((size_t)q * N + n0 + idx) * 8;
        lAh[i] = (void*)&Ahs[(size_t)c * 8];
        lAl[i] = (void*)&Als[(size_t)c * 8];
        lBh[i] = (void*)&Bhs[(size_t)c * 8];
        lBl[i] = (void*)&Bls[(size_t)c * 8];
    }

    f32x4 acc[4][4];
    #pragma unroll
    for (int mi = 0; mi < 4; ++mi)
        #pragma unroll
        for (int ni = 0; ni < 4; ++ni)
            acc[mi][ni] = (f32x4){0.f, 0.f, 0.f, 0.f};

    const size_t bstep = (size_t)4 * N * 8;
    for (int ks = 0; ks < K / 32; ++ks) {
        __syncthreads();
        #pragma unroll
        for (int i = 0; i < 2; ++i) {
            gload_lds16(gAh[i], lAh[i]);
            gload_lds16(gAl[i], lAl[i]);
            gload_lds16(gBh[i], lBh[i]);
            gload_lds16(gBl[i], lBl[i]);
            gAh[i] += 32; gAl[i] += 32; gBh[i] += bstep; gBl[i] += bstep;
        }
        __syncthreads();

        bf16x8 ah[4], al[4], bh[4], bl[4];
        #pragma unroll
        for (int mi = 0; mi < 4; ++mi) {
            ah[mi] = *(const bf16x8*)&Ahs[((size_t)quad * 128 + wm + mi * 16 + l16) * 8];
            al[mi] = *(const bf16x8*)&Als[((size_t)quad * 128 + wm + mi * 16 + l16) * 8];
        }
        #pragma unroll
        for (int ni = 0; ni < 4; ++ni) {
            bh[ni] = *(const bf16x8*)&Bhs[((size_t)quad * 128 + wn + ni * 16 + l16) * 8];
            bl[ni] = *(const bf16x8*)&Bls[((size_t)quad * 128 + wn + ni * 16 + l16) * 8];
        }
        #pragma unroll
        for (int mi = 0; mi < 4; ++mi)
            #pragma unroll
            for (int ni = 0; ni < 4; ++ni) {
                acc[mi][ni] = __builtin_amdgcn_mfma_f32_16x16x32_bf16(
                    ah[mi], bh[ni], acc[mi][ni], 0, 0, 0);
                acc[mi][ni] = __builtin_amdgcn_mfma_f32_16x16x32_bf16(
                    ah[mi], bl[ni], acc[mi][ni], 0, 0, 0);
                acc[mi][ni] = __builtin_amdgcn_mfma_f32_16x16x32_bf16(
                    al[mi], bh[ni], acc[mi][ni], 0, 0, 0);
            }
    }

    // epilogue: C/D layout col=l16, row=quad*4+reg
    #pragma unroll
    for (int mi = 0; mi < 4; ++mi) {
        const int rbase = wm + mi * 16 + quad * 4;
        #pragma unroll
        for (int r = 0; r < 4; ++r) {
            const size_t gm = m0 + rbase + r;
            #pragma unroll
            for (int ni = 0; ni < 4; ++ni) {
                const int col = n0 + wn + ni * 16 + l16;
                float vv = acc[mi][ni][r] + bp[col];
                if (RESID) vv += resid[gm * N + col];
                Cp[gm * N + col] = vv;
            }
        }
    }
}

// ---------------- MFMA flash attention (bf16x3 split precision) -------------
// Block: 128 q-rows, 4 waves x 32 q. Per kv-tile (64 rows):
//   S^T = K·Q^T via mfma_32x32x16 (3 passes Kh·Qh + Kh·Ql + Kl·Qh)
//   -> lane-local online softmax (q = lane&31)
//   -> P hi/lo frags built in-register (cross-half shfl_xor exchange)
//   -> O^T += V^T·P (3 passes Vh·Ph + Vh·Pl + Vl·Ph)
// K LDS: [doct][row][8] pad-520; V LDS: transposed [d][j] with octet XOR
// swizzle (j>>3)^(d&7) so PV ds_read_b128 avoids stride-128B conflicts.
// T14: next tile's K/V global loads issued before compute, written next iter.
__global__ __launch_bounds__(256, 2)
void attn_kernel(const float* __restrict__ q, const float* __restrict__ k,
                 const float* __restrict__ v,
                 unsigned short* __restrict__ oh, unsigned short* __restrict__ ol)
{
    struct KV {
        unsigned short Kp[2][4160];   // [plane][doct*520 + row*8 + (d&7)]
        unsigned short Vp[2][4096];   // [plane][d*64 + ((j>>3)^(d&7))*8 + (j&7)]
    };
    __shared__ union SMem { KV kv; float O[4 * 64 * 33]; } sm;
    __shared__ float linv[128];

    const int qt = blockIdx.x, hh = blockIdx.y, b = blockIdx.z;
    const int tid = threadIdx.x;
    const int lane = tid & 63, w = tid >> 6;
    const int l31 = lane & 31, hf = lane >> 5;

    const size_t rowbase = (size_t)b * NS;
    const size_t cb = (size_t)hh * HD;

    // ---- issue tile-0 K/V loads ------------------------------------------
    float4 kreg[4], vreg[2][2];
    auto loadKV = [&](int kt) {
        #pragma unroll
        for (int i = 0; i < 4; ++i) {
            const int c = tid + 256 * i, j = c >> 4, d4 = (c & 15) << 2;
            kreg[i] = *(const float4*)(k + (rowbase + kt * 64 + j) * NHID + cb + d4);
        }
        #pragma unroll
        for (int i = 0; i < 2; ++i) {
            const int c = tid + 256 * i;
            const int j2 = ((c >> 6) << 3) + (((c >> 4) & 3) << 1);
            const int d4 = (c & 15) << 2;
            vreg[i][0] = *(const float4*)(v + (rowbase + kt * 64 + j2) * NHID + cb + d4);
            vreg[i][1] = *(const float4*)(v + (rowbase + kt * 64 + j2 + 1) * NHID + cb + d4);
        }
    };
    loadKV(0);

    // ---- Q fragments in registers (hi/lo), 1/sqrt(D) folded ---------------
    // B-operand layout: lane holds Q[qb + l31][16s + 8hf + e]
    bf16x8 qfh[4], qfl[4];
    {
        const int qrow = qt * 128 + w * 32 + l31;
        const float* qp = q + (rowbase + qrow) * NHID + cb + hf * 8;
        #pragma unroll
        for (int s = 0; s < 4; ++s) {
            const float4 f0 = *(const float4*)(qp + s * 16);
            const float4 f1 = *(const float4*)(qp + s * 16 + 4);
            const float ff[8] = {f0.x, f0.y, f0.z, f0.w, f1.x, f1.y, f1.z, f1.w};
            #pragma unroll
            for (int e = 0; e < 8; ++e) {
                const float sv = ff[e] * 0.125f;
                const unsigned short hv = f2bf(sv);
                qfh[s][e] = (short)hv;
                qfl[s][e] = (short)f2bf(sv - bf2f(hv));
            }
        }
    }

    f32x16 oa[2];
    #pragma unroll
    for (int mfd = 0; mfd < 2; ++mfd)
        #pragma unroll
        for (int r = 0; r < 16; ++r) oa[mfd][r] = 0.f;
    float m_run = -1e30f, l_run = 0.f;

    for (int kt = 0; kt < NS / 64; ++kt) {
        __syncthreads();   // previous tile's LDS reads done

        // ---- write staged K (hi/lo, gemm layout, pad 520) -----------------
        #pragma unroll
        for (int i = 0; i < 4; ++i) {
            const int c = tid + 256 * i, j = c >> 4, d4 = (c & 15) << 2;
            const float* f = (const float*)&kreg[i];
            unsigned short hs[4], ls[4];
            #pragma unroll
            for (int e = 0; e < 4; ++e) {
                hs[e] = f2bf(f[e]); ls[e] = f2bf(f[e] - bf2f(hs[e]));
            }
            u32x2 wh, wl;
            wh[0] = hs[0] | ((unsigned)hs[1] << 16); wh[1] = hs[2] | ((unsigned)hs[3] << 16);
            wl[0] = ls[0] | ((unsigned)ls[1] << 16); wl[1] = ls[2] | ((unsigned)ls[3] << 16);
            const int ad = (d4 >> 3) * 520 + j * 8 + (d4 & 7);
            *(u32x2*)&sm.kv.Kp[0][ad] = wh;
            *(u32x2*)&sm.kv.Kp[1][ad] = wl;
        }
        // ---- write staged V (transposed + octet swizzle, hi/lo) -----------
        #pragma unroll
        for (int i = 0; i < 2; ++i) {
            const int c = tid + 256 * i;
            const int j2 = ((c >> 6) << 3) + (((c >> 4) & 3) << 1);
            const int d4 = (c & 15) << 2;
            const float* fa = (const float*)&vreg[i][0];
            const float* fb = (const float*)&vreg[i][1];
            #pragma unroll
            for (int dd = 0; dd < 4; ++dd) {
                const int d = d4 + dd;
                const unsigned short ah_ = f2bf(fa[dd]), bh_ = f2bf(fb[dd]);
                const unsigned short al_ = f2bf(fa[dd] - bf2f(ah_));
                const unsigned short bl_ = f2bf(fb[dd] - bf2f(bh_));
                const int ad = d * 64 + (((j2 >> 3) ^ (d & 7)) << 3) + (j2 & 7);
                *(unsigned*)&sm.kv.Vp[0][ad] = ah_ | ((unsigned)bh_ << 16);
                *(unsigned*)&sm.kv.Vp[1][ad] = al_ | ((unsigned)bl_ << 16);
            }
        }
        if (kt + 1 < NS / 64) loadKV(kt + 1);   // T14: hide HBM under compute
        __syncthreads();   // LDS ready

        // ---- S^T = K·Q^T, 3 passes ---------------------------------------
        f32x16 sa[2];
        #pragma unroll
        for (int mf = 0; mf < 2; ++mf)
            #pragma unroll
            for (int r = 0; r < 16; ++r) sa[mf][r] = 0.f;
        #pragma unroll
        for (int mf = 0; mf < 2; ++mf) {
            bf16x8 kf[4];
            #pragma unroll
            for (int s = 0; s < 4; ++s)
                kf[s] = *(const bf16x8*)&sm.kv.Kp[0][(2*s+hf)*520 + (mf*32+l31)*8];
            #pragma unroll
            for (int s = 0; s < 4; ++s)
                sa[mf] = __builtin_amdgcn_mfma_f32_32x32x16_bf16(kf[s], qfh[s], sa[mf], 0, 0, 0);
            #pragma unroll
            for (int s = 0; s < 4; ++s)
                sa[mf] = __builtin_amdgcn_mfma_f32_32x32x16_bf16(kf[s], qfl[s], sa[mf], 0, 0, 0);
            #pragma unroll
            for (int s = 0; s < 4; ++s)
                kf[s] = *(const bf16x8*)&sm.kv.Kp[1][(2*s+hf)*520 + (mf*32+l31)*8];
            #pragma unroll
            for (int s = 0; s < 4; ++s)
                sa[mf] = __builtin_amdgcn_mfma_f32_32x32x16_bf16(kf[s], qfh[s], sa[mf], 0, 0, 0);
        }

        // ---- online softmax: lane owns row q = qb + l31 -------------------
        float tm = sa[0][0];
        #pragma unroll
        for (int r = 1; r < 16; ++r) tm = fmaxf(tm, sa[0][r]);
        #pragma unroll
        for (int r = 0; r < 16; ++r) tm = fmaxf(tm, sa[1][r]);
        tm = fmaxf(tm, __shfl_xor(tm, 32));
        const float newm = fmaxf(m_run, tm);
        const float al = __expf(m_run - newm);
        m_run = newm;
        float ps = 0.f;
        #pragma unroll
        for (int mf = 0; mf < 2; ++mf)
            #pragma unroll
            for (int r = 0; r < 16; ++r) {
                const float pv = __expf(sa[mf][r] - newm);
                sa[mf][r] = pv; ps += pv;
            }
        ps += __shfl_xor(ps, 32);
        l_run = l_run * al + ps;
        #pragma unroll
        for (int mfd = 0; mfd < 2; ++mfd)
            #pragma unroll
            for (int r = 0; r < 16; ++r) oa[mfd][r] *= al;

        // ---- P fragments (hi/lo) via cross-half exchange ------------------
        // frag for j-step t: lane element e <-> j = 16t + 8hf + e
        bf16x8 pfh[4], pfl[4];
        #pragma unroll
        for (int t = 0; t < 4; ++t) {
            const int mfp = t >> 1, u8 = (t & 1) * 8;
            unsigned short hb[8]; float lo8[8];
            #pragma unroll
            for (int e = 0; e < 8; ++e) {
                const float pv = sa[mfp][u8 + e];
                hb[e] = f2bf(pv); lo8[e] = pv - bf2f(hb[e]);
            }
            {
                const unsigned X0 = hb[0] | ((unsigned)hb[1] << 16);
                const unsigned X1 = hb[2] | ((unsigned)hb[3] << 16);
                const unsigned X2 = hb[4] | ((unsigned)hb[5] << 16);
                const unsigned X3 = hb[6] | ((unsigned)hb[7] << 16);
                const unsigned s0 = (unsigned)__shfl_xor((int)X0, 32);
                const unsigned s1 = (unsigned)__shfl_xor((int)X1, 32);
                const unsigned s2 = (unsigned)__shfl_xor((int)X2, 32);
                const unsigned s3 = (unsigned)__shfl_xor((int)X3, 32);
                union UU { unsigned wd[4]; bf16x8 vv; } uu;
                uu.wd[0] = hf ? s2 : X0;
                uu.wd[1] = hf ? s3 : X1;
                uu.wd[2] = hf ? X2 : s0;
                uu.wd[3] = hf ? X3 : s1;
                pfh[t] = uu.vv;
            }
            {
                unsigned short lb[8];
                #pragma unroll
                for (int e = 0; e < 8; ++e) lb[e] = f2bf(lo8[e]);
                const unsigned Y0 = lb[0] | ((unsigned)lb[1] << 16);
                const unsigned Y1 = lb[2] | ((unsigned)lb[3] << 16);
                const unsigned Y2 = lb[4] | ((unsigned)lb[5] << 16);
                const unsigned Y3 = lb[6] | ((unsigned)lb[7] << 16);
                const unsigned s0 = (unsigned)__shfl_xor((int)Y0, 32);
                const unsigned s1 = (unsigned)__shfl_xor((int)Y1, 32);
                const unsigned s2 = (unsigned)__shfl_xor((int)Y2, 32);
                const unsigned s3 = (unsigned)__shfl_xor((int)Y3, 32);
                union UU { unsigned wd[4]; bf16x8 vv; } uu;
                uu.wd[0] = hf ? s2 : Y0;
                uu.wd[1] = hf ? s3 : Y1;
                uu.wd[2] = hf ? Y2 : s0;
                uu.wd[3] = hf ? Y3 : s1;
                pfl[t] = uu.vv;
            }
        }

        // ---- O^T += V^T·P, 3 passes --------------------------------------
        #pragma unroll
        for (int mfd = 0; mfd < 2; ++mfd) {
            const int db = (mfd * 32 + l31) * 64;
            const int sw = l31 & 7;           // d&7 for this lane
            bf16x8 vf[4];
            #pragma unroll
            for (int ks = 0; ks < 4; ++ks)
                vf[ks] = *(const bf16x8*)&sm.kv.Vp[0][db + (((2*ks+hf) ^ sw) << 3)];
            #pragma unroll
            for (int ks = 0; ks < 4; ++ks)
                oa[mfd] = __builtin_amdgcn_mfma_f32_32x32x16_bf16(vf[ks], pfh[ks], oa[mfd], 0, 0, 0);
            #pragma unroll
            for (int ks = 0; ks < 4; ++ks)
                oa[mfd] = __builtin_amdgcn_mfma_f32_32x32x16_bf16(vf[ks], pfl[ks], oa[mfd], 0, 0, 0);
            #pragma unroll
            for (int ks = 0; ks < 4; ++ks)
                vf[ks] = *(const bf16x8*)&sm.kv.Vp[1][db + (((2*ks+hf) ^ sw) << 3)];
            #pragma unroll
            for (int ks = 0; ks < 4; ++ks)
                oa[mfd] = __builtin_amdgcn_mfma_f32_32x32x16_bf16(vf[ks], pfh[ks], oa[mfd], 0, 0, 0);
        }
    }

    // ---- epilogue: O^T -> padded LDS -> normalized hi/lo bf16 stores ------
    __syncthreads();   // done reading K/V LDS; overlay with O
    {
        float* Ow = sm.O + w * (64 * 33);
        #pragma unroll
        for (int mfd = 0; mfd < 2; ++mfd)
            #pragma unroll
            for (int r = 0; r < 16; ++r) {
                const int dr = mfd * 32 + (r & 3) + 8 * (r >> 2) + 4 * hf;
                Ow[dr * 33 + l31] = oa[mfd][r];
            }
        if (hf == 0) linv[w * 32 + l31] = 1.0f / l_run;
    }
    __syncthreads();
    #pragma unroll
    for (int it = 0; it < 8; ++it) {
        const int c = tid + 256 * it;
        const int qq = c >> 4, d4 = (c & 15) << 2;
        const float* Or = sm.O + (qq >> 5) * (64 * 33) + (qq & 31);
        const float sc_ = linv[qq];
        unsigned short hs[4], ls[4];
        #pragma unroll
        for (int e = 0; e < 4; ++e) {
            const float vv = Or[(d4 + e) * 33] * sc_;
            hs[e] = f2bf(vv); ls[e] = f2bf(vv - bf2f(hs[e]));
        }
        u32x2 ph_, pl_;
        ph_[0] = hs[0] | ((unsigned)hs[1] << 16); ph_[1] = hs[2] | ((unsigned)hs[3] << 16);
        pl_[0] = ls[0] | ((unsigned)ls[1] << 16); pl_[1] = ls[2] | ((unsigned)ls[3] << 16);
        const size_t o = (rowbase + qt * 128 + qq) * NHID + cb + d4;
        *(u32x2*)&oh[o] = ph_;
        *(u32x2*)&ol[o] = pl_;
    }
}

// ---------------- Gate: fp32 logits, argmax (first-max), token scatter ------
__global__ __launch_bounds__(64)
void gate_kernel(const float* __restrict__ hn2, const float* __restrict__ gw,
                 const float* __restrict__ gb, int* __restrict__ counts,
                 int* __restrict__ tok)
{
    const int t = blockIdx.x, lane = threadIdx.x;
    const float* row = hn2 + (size_t)t * NHID;
    float acc[NE] = {};
    for (int hh = lane; hh < NHID; hh += 64) {
        const float xv = row[hh];
        const float4 g0 = ((const float4*)(gw + (size_t)hh * NE))[0];
        const float4 g1 = ((const float4*)(gw + (size_t)hh * NE))[1];
        acc[0] += xv * g0.x; acc[1] += xv * g0.y; acc[2] += xv * g0.z; acc[3] += xv * g0.w;
        acc[4] += xv * g1.x; acc[5] += xv * g1.y; acc[6] += xv * g1.z; acc[7] += xv * g1.w;
    }
    #pragma unroll
    for (int e = 0; e < NE; ++e)
        for (int off = 32; off > 0; off >>= 1)
            acc[e] += __shfl_down(acc[e], off);
    if (lane == 0) {
        float best = -1e30f; int bi = 0;
        #pragma unroll
        for (int e = 0; e < NE; ++e) {
            const float lv = acc[e] + gb[e];
            if (lv > best) { best = lv; bi = e; }   // strict >: first-max (jnp.argmax)
        }
        const int pos = atomicAdd(&counts[bi], 1);
        tok[(size_t)bi * NT + pos] = t;
    }
}

// ---------------- MoE grouped GEMM (R5) ------------------------------------
// Grid: 1D, id -> { e = id%8 (XCD pin), nb = (id/8)%nn, r0 = (id/8)/nn }.
// Block loops m-tiles mt = r0, r0+MSPLIT, ... of expert e => weights streamed
// ~once from HBM (same-(e,nb) r-blocks + successive mt reuse via XCD L2).
// K-loop: 1-barrier double-buffer (stage k+1 into buf^1 || compute buf).
template<int BN, int MSPLIT, bool BF16OUT>
__global__ __launch_bounds__(256, 2)
void moe_gemm(const unsigned short* __restrict__ A,   // bf16 [NT][K]
              const unsigned short* __restrict__ Bp,  // bf16 packed [E][K/8][N][8]
              const float* __restrict__ bias,         // [E][N]
              const float* __restrict__ resid,        // [NT][N] or null
              void* __restrict__ Cout,                // bf16 or fp32 [NT][N]
              int N, int K,
              const int* __restrict__ rows, const int* __restrict__ counts)
{
    constexpr int NI = BN / 32;
    constexpr int NBCH = (4 * BN) / 256;
    __shared__ __attribute__((aligned(16))) unsigned short As[2][4 * 128 * 8];
    __shared__ __attribute__((aligned(16))) unsigned short Bs[2][4 * BN * 8];

    const int id = blockIdx.x;
    const int e  = id & 7;                 // expert -> XCD (round-robin dispatch)
    const int nn = N / BN;
    const int nb = (id >> 3) % nn;
    const int r0 = (id >> 3) / nn;
    const int n0 = nb * BN;

    const int Meff = counts[e];
    const int* rl = rows + (size_t)e * NT;
    const int nmt = (Meff + 127) >> 7;     // m-tiles for this expert

    const int tid  = threadIdx.x;
    const int lane = tid & 63, wid = tid >> 6;
    const int quad = lane >> 4, l16 = lane & 15;
    const int wm = (wid >> 1) * 64;
    const int wn = (wid & 1) * (BN / 2);
    const int NK = K / 32;
    const size_t bstep = (size_t)4 * N * 8;

    for (int mt = r0; mt < nmt; mt += MSPLIT) {
        const int m0 = mt * 128;

        const unsigned short* gA[2];
        #pragma unroll
        for (int i = 0; i < 2; ++i) {
            const int c = tid + 256 * i;
            const int q = c >> 7, row = c & 127;
            int m = m0 + row; if (m >= Meff) m = Meff - 1;
            gA[i] = A + (size_t)rl[m] * K + q * 8;
        }
        const unsigned short* gB[NBCH];
        #pragma unroll
        for (int i = 0; i < NBCH; ++i) {
            const int c = tid + 256 * i;
            const int q = c / BN, n = c % BN;
            gB[i] = Bp + (((size_t)e * (K / 8) + q) * N + n0 + n) * 8;
        }

        f32x4 acc[4][NI];
        #pragma unroll
        for (int mi = 0; mi < 4; ++mi)
            #pragma unroll
            for (int ni = 0; ni < NI; ++ni)
                acc[mi][ni] = (f32x4){0.f, 0.f, 0.f, 0.f};

        // prologue: stage k-step 0 -> buf 0
        gload_lds16(gA[0], (void*)&As[0][(size_t)tid * 8]);
        gload_lds16(gA[1], (void*)&As[0][(size_t)(tid + 256) * 8]);
        #pragma unroll
        for (int i = 0; i < NBCH; ++i)
            gload_lds16(gB[i], (void*)&Bs[0][(size_t)(tid + 256 * i) * 8]);
        gA[0] += 32; gA[1] += 32;
        #pragma unroll
        for (int i = 0; i < NBCH; ++i) gB[i] += bstep;
        __syncthreads();

        for (int ks = 0; ks < NK; ++ks) {
            const int cur = ks & 1, nxt = cur ^ 1;
            if (ks + 1 < NK) {             // stage next tile (overlaps MFMA)
                gload_lds16(gA[0], (void*)&As[nxt][(size_t)tid * 8]);
                gload_lds16(gA[1], (void*)&As[nxt][(size_t)(tid + 256) * 8]);
                #pragma unroll
                for (int i = 0; i < NBCH; ++i)
                    gload_lds16(gB[i], (void*)&Bs[nxt][(size_t)(tid + 256 * i) * 8]);
                gA[0] += 32; gA[1] += 32;
                #pragma unroll
                for (int i = 0; i < NBCH; ++i) gB[i] += bstep;
            }

            bf16x8 af[4], bfr[NI];
            #pragma unroll
            for (int mi = 0; mi < 4; ++mi)
                af[mi] = *(const bf16x8*)&As[cur][((size_t)quad * 128 + wm + mi * 16 + l16) * 8];
            #pragma unroll
            for (int ni = 0; ni < NI; ++ni)
                bfr[ni] = *(const bf16x8*)&Bs[cur][((size_t)quad * BN + wn + ni * 16 + l16) * 8];
            #pragma unroll
            for (int mi = 0; mi < 4; ++mi)
                #pragma unroll
                for (int ni = 0; ni < NI; ++ni)
                    acc[mi][ni] = __builtin_amdgcn_mfma_f32_16x16x32_bf16(
                        af[mi], bfr[ni], acc[mi][ni], 0, 0, 0);
            __syncthreads();               // staged(k+1) ready; reads(k) done
        }

        #pragma unroll
        for (int mi = 0; mi < 4; ++mi) {
            const int rbase = wm + mi * 16 + quad * 4;
            #pragma unroll
            for (int r = 0; r < 4; ++r) {
                const int m = m0 + rbase + r;
                if (m >= Meff) continue;
                const int gr = rl[m];
                #pragma unroll
                for (int ni = 0; ni < NI; ++ni) {
                    const int col = n0 + wn + ni * 16 + l16;
                    float vv = acc[mi][ni][r] + bias[(size_t)e * N + col];
                    if (BF16OUT) {
                        vv = fmaxf(vv, 0.f);
                        ((unsigned short*)Cout)[(size_t)gr * N + col] = f2bf(vv);
                    } else {
                        vv += resid[(size_t)gr * N + col];
                        ((float*)Cout)[(size_t)gr * N + col] = vv;
                    }
                }
            }
        }
    }
}

// ---------------------------------------------------------------------------
extern "C" void kernel_launch(void* const* d_in, const int* in_sizes, int n_in,
                              void* d_out, int out_size, void* d_ws, size_t ws_size,
                              hipStream_t stream)
{
    (void)in_sizes; (void)n_in; (void)out_size; (void)ws_size;
    const float* x      = (const float*)d_in[0];
    const float* ln1_g  = (const float*)d_in[1];
    const float* ln1_b  = (const float*)d_in[2];
    const float* ln2_g  = (const float*)d_in[3];
    const float* ln2_b  = (const float*)d_in[4];
    const float* wq     = (const float*)d_in[5];
    const float* bq     = (const float*)d_in[6];
    const float* wk     = (const float*)d_in[7];
    const float* bk     = (const float*)d_in[8];
    const float* wv     = (const float*)d_in[9];
    const float* bv     = (const float*)d_in[10];
    const float* wo     = (const float*)d_in[11];
    const float* bo     = (const float*)d_in[12];
    const float* gate_w = (const float*)d_in[13];
    const float* gate_b = (const float*)d_in[14];
    const float* w1     = (const float*)d_in[15];
    const float* b1     = (const float*)d_in[16];
    const float* w2     = (const float*)d_in[17];
    const float* b2     = (const float*)d_in[18];
    float* out = (float*)d_out;

    // workspace layout (128 MiB total; R1 proved 128.13 MiB ok):
    //  0-16   q        -> (after Wo) MoE wpack [0,64)
    //  16-32  k
    //  32-48  v
    //  48-56  hnh      -> (after QKV) oh
    //  56-64  hnl      -> ol
    //  64-76  qkv weight packs (hi+lo, 4 MiB each) -> (after Wo) hn2bf 64-72
    //  72-76  (dead wv pack) -> tok (128 KB) + cnts
    //  76-80  wo pack
    //  80-96  x2 (alive to end)
    //  96-112 hn2f     -> (after gate) mid low half
    //  96-128 mid bf16 [NT][NF]
    char* W8 = (char*)d_ws;
    float*          qbuf   = (float*)(W8);
    float*          kbuf   = (float*)(W8 + 16 * MiB);
    float*          vbuf   = (float*)(W8 + 32 * MiB);
    unsigned short* hnh    = (unsigned short*)(W8 + 48 * MiB);
    unsigned short* hnl    = (unsigned short*)(W8 + 56 * MiB);
    unsigned short* ohb    = (unsigned short*)(W8 + 48 * MiB);
    unsigned short* olb    = (unsigned short*)(W8 + 56 * MiB);
    unsigned short* qkvpk  = (unsigned short*)(W8 + 64 * MiB);   // [3][2][128][1024][8]
    unsigned short* wopk   = (unsigned short*)(W8 + 76 * MiB);
    unsigned short* hn2bf  = (unsigned short*)(W8 + 64 * MiB);
    int*            tok    = (int*)(W8 + 72 * MiB);
    int*            cnts   = (int*)(W8 + 72 * MiB + (size_t)NE * NT * 4);
    float*          x2buf  = (float*)(W8 + 80 * MiB);
    float*          hn2f   = (float*)(W8 + 96 * MiB);
    unsigned short* mid    = (unsigned short*)(W8 + 96 * MiB);
    unsigned short* wpack  = (unsigned short*)(W8);              // MoE, 64 MiB

    const size_t wsz = (size_t)2 * NHID * NHID;   // elems per packed weight (hi+lo)

    // 0. pack QKV + Wo weights -> hi/lo bf16 planes
    {
        dim3 g(NHID / 256, NHID / 8, 1);
        pack_whl<<<g, 256, 0, stream>>>(wq, qkvpk,           NHID, NHID);
        pack_whl<<<g, 256, 0, stream>>>(wk, qkvpk + wsz,     NHID, NHID);
        pack_whl<<<g, 256, 0, stream>>>(wv, qkvpk + 2 * wsz, NHID, NHID);
        pack_whl<<<g, 256, 0, stream>>>(wo, wopk,            NHID, NHID);
    }

    // 1. LN1(x) -> hi/lo planes
    ln_kernel<0><<<NT, 256, 0, stream>>>(x, ln1_g, ln1_b, nullptr, hnh, hnl);

    // 2. q,k,v = hn @ {wq,wk,wv} + bias   (bf16x3 MFMA, fused over z)
    {
        dim3 g(NHID / 128, NT / 128, 3);
        gemm3<true, false><<<g, 256, 0, stream>>>(
            hnh, hnl, qkvpk, bq, bk, bv, nullptr, qbuf, NHID, NHID);
    }

    // 3. o = attention(q,k,v) -> hi/lo planes (overwrites hnh/hnl)
    {
        dim3 g(NS / 128, NHEAD, NB);
        attn_kernel<<<g, 256, 0, stream>>>(qbuf, kbuf, vbuf, ohb, olb);
    }

    // 4. x2 = x + o @ wo + bo   (bf16x3 MFMA)
    {
        dim3 g(NHID / 128, NT / 128, 1);
        gemm3<false, true><<<g, 256, 0, stream>>>(
            ohb, olb, wopk, bo, nullptr, nullptr, x, x2buf, NHID, NHID);
    }

    // 5. hn2 = LN2(x2) -> fp32 (gate) + bf16 hi (MoE A)
    ln_kernel<1><<<NT, 256, 0, stream>>>(x2buf, ln2_g, ln2_b, hn2f, hn2bf, nullptr);

    // 6. top-1 routing (fp32)
    hipMemsetAsync(cnts, 0, NE * sizeof(int), stream);
    gate_kernel<<<NT, 64, 0, stream>>>(hn2f, gate_w, gate_b, cnts, tok);

    // 7. pack w1 (hi only) -> wpack (overwrites q/k/v/oh/ol; all dead)
    {
        dim3 g(NF / 256, NHID / 8, NE);
        pack_w<<<g, 256, 0, stream>>>(w1, wpack, NHID, NF);
    }
    // 8. mid = relu(gather(hn2bf) @ w1[e] + b1[e])  (bf16 out; overlays hn2f)
    //    grid: 8 experts x 32 n-blocks x MSPLIT 2 = 512 blocks (2/CU)
    moe_gemm<128, 2, true><<<NE * (NF / 128) * 2, 256, 0, stream>>>(
        hn2bf, wpack, b1, nullptr, mid, NF, NHID, tok, cnts);
    // 9. pack w2 (GEMM1 done with w1 pack)
    {
        dim3 g(NHID / 256, NF / 8, NE);
        pack_w<<<g, 256, 0, stream>>>(w2, wpack, NF, NHID);
    }
    // 10. out = x2 + gather(mid) @ w2[e] + b2[e]
    //     grid: 8 experts x 16 n-blocks x MSPLIT 4 = 512 blocks (2/CU)
    moe_gemm<64, 4, false><<<NE * (NHID / 64) * 4, 256, 0, stream>>>(
        mid, wpack, b2, x2buf, out, NHID, NF, tok, cnts);
}

// Round 3
// 839.685 us; speedup vs baseline: 1.5245x; 1.0988x over previous
//
#include <hip/hip_runtime.h>
#include <math.h>

// ---------------------------------------------------------------------------
// TransformerBlock: LN -> QKV -> MHA -> Wo(+resid) -> LN -> top1-MoE(+resid)
// R6: moe_gemm gets a depth-2 counted-vmcnt pipeline (T4): 3 LDS buffers,
// stage tile k+2 each iter, raw s_barrier + s_waitcnt vmcnt(W) (never 0 in
// the main loop) so global_load_lds stays in flight across barriers. R5's
// 2-phase loop drained vmcnt every k-step -> ~4700 cyc/step, 188us each.
// Also MSPLIT 3/5 for chain balance + 3-4 blocks/CU. Rest unchanged.
// ---------------------------------------------------------------------------

constexpr int NB = 4, NS = 1024, NHID = 1024, NHEAD = 16, HD = 64, NE = 8, NF = 4096;
constexpr int NT = NB * NS;          // 4096 tokens
constexpr float LN_EPS = 1e-5f;
constexpr size_t MiB = 1048576;

using bf16x8 = __attribute__((ext_vector_type(8))) short;
using f32x4  = __attribute__((ext_vector_type(4))) float;
using f32x16 = __attribute__((ext_vector_type(16))) float;
using u32x2  = __attribute__((ext_vector_type(2))) unsigned int;

__device__ __forceinline__ unsigned short f2bf(float x) {
    unsigned u = __float_as_uint(x);
    return (unsigned short)((u + 0x7fffu + ((u >> 16) & 1u)) >> 16);   // RNE
}
__device__ __forceinline__ float bf2f(unsigned short h) {
    return __uint_as_float((unsigned)h << 16);
}

__device__ __forceinline__ void gload_lds16(const void* g, void* l) {
    __builtin_amdgcn_global_load_lds(
        (const __attribute__((address_space(1))) void*)g,
        (__attribute__((address_space(3))) void*)l, 16, 0, 0);
}

// ---------------- LayerNorm ------------------------------------------------
// MODE 0: write hi+lo bf16 planes only (feeds bf16x3 GEMM)
// MODE 1: write fp32 (gate) + hi bf16 plane (feeds 1-pass MoE GEMM)
template<int MODE>
__global__ __launch_bounds__(256)
void ln_kernel(const float* __restrict__ x, const float* __restrict__ g,
               const float* __restrict__ b, float* __restrict__ y,
               unsigned short* __restrict__ yh, unsigned short* __restrict__ yl)
{
    const int t = blockIdx.x, tid = threadIdx.x;
    const float4 xv = ((const float4*)(x + (size_t)t * NHID))[tid];
    float s  = xv.x + xv.y + xv.z + xv.w;
    float sq = xv.x*xv.x + xv.y*xv.y + xv.z*xv.z + xv.w*xv.w;
    for (int off = 32; off > 0; off >>= 1) {
        s  += __shfl_down(s, off);
        sq += __shfl_down(sq, off);
    }
    __shared__ float ws_[4], wsq_[4], stats[2];
    const int wid = tid >> 6, lane = tid & 63;
    if (lane == 0) { ws_[wid] = s; wsq_[wid] = sq; }
    __syncthreads();
    if (tid == 0) {
        const float ts = ws_[0] + ws_[1] + ws_[2] + ws_[3];
        const float tq = wsq_[0] + wsq_[1] + wsq_[2] + wsq_[3];
        const float mu = ts * (1.0f / NHID);
        const float var = tq * (1.0f / NHID) - mu * mu;
        stats[0] = mu; stats[1] = rsqrtf(var + LN_EPS);
    }
    __syncthreads();
    const float mu = stats[0], rs = stats[1];
    const float4 gv = ((const float4*)g)[tid];
    const float4 bv = ((const float4*)b)[tid];
    float ov[4];
    ov[0] = (xv.x - mu) * rs * gv.x + bv.x;
    ov[1] = (xv.y - mu) * rs * gv.y + bv.y;
    ov[2] = (xv.z - mu) * rs * gv.z + bv.z;
    ov[3] = (xv.w - mu) * rs * gv.w + bv.w;
    if (MODE == 1) {
        float4 o4; o4.x = ov[0]; o4.y = ov[1]; o4.z = ov[2]; o4.w = ov[3];
        ((float4*)(y + (size_t)t * NHID))[tid] = o4;
    }
    unsigned long long ph = 0, pl = 0;
    #pragma unroll
    for (int j = 0; j < 4; ++j) {
        const unsigned short h = f2bf(ov[j]);
        ph |= (unsigned long long)h << (16 * j);
        if (MODE == 0) pl |= (unsigned long long)f2bf(ov[j] - bf2f(h)) << (16 * j);
    }
    ((unsigned long long*)(yh + (size_t)t * NHID))[tid] = ph;
    if (MODE == 0)
        ((unsigned long long*)(yl + (size_t)t * NHID))[tid] = pl;
}

// ---------------- Pack weight fp32 [K][N] -> bf16 [2][K/8][N][8] (hi,lo) ---
__global__ __launch_bounds__(256)
void pack_whl(const float* __restrict__ w, unsigned short* __restrict__ out,
              int K, int N)
{
    const int k8 = blockIdx.y;
    const int col = blockIdx.x * 256 + threadIdx.x;
    const float* src = w + (size_t)k8 * 8 * N + col;
    unsigned short th[8] __attribute__((aligned(16)));
    unsigned short tl[8] __attribute__((aligned(16)));
    #pragma unroll
    for (int j = 0; j < 8; ++j) {
        const float f = src[(size_t)j * N];
        th[j] = f2bf(f);
        tl[j] = f2bf(f - bf2f(th[j]));
    }
    const size_t plane = (size_t)(K / 8) * N * 8;
    const size_t o = ((size_t)k8 * N + col) * 8;
    *(f32x4*)(out + o)         = *(const f32x4*)th;
    *(f32x4*)(out + plane + o) = *(const f32x4*)tl;
}

// ---------------- Pack weight fp32 [E][K][N] -> bf16 [E][K/8][N][8] (hi) ---
__global__ __launch_bounds__(256)
void pack_w(const float* __restrict__ w, unsigned short* __restrict__ out,
            int K, int N)
{
    const int e = blockIdx.z, k8 = blockIdx.y;
    const int col = blockIdx.x * 256 + threadIdx.x;
    const float* src = w + ((size_t)e * K + (size_t)k8 * 8) * N + col;
    unsigned short tmp[8] __attribute__((aligned(16)));
    #pragma unroll
    for (int j = 0; j < 8; ++j) tmp[j] = f2bf(src[(size_t)j * N]);
    *(f32x4*)(out + (((size_t)e * (K / 8) + k8) * N + col) * 8) = *(const f32x4*)tmp;
}

// ---------------- bf16x3 MFMA GEMM: C = A @ W + bias (+resid) --------------
// A as hi/lo bf16 planes [M][K]; W packed [2][K/8][N][8] (hi,lo).
// BM=BN=128, BK=32, 256 thr (4 waves, 2x2). 3 MFMA passes: hh, hl, lh.
// QKV3: blockIdx.z selects weight z (stride 2*(K/8)*N*8), bias z, C + z*NT*N.
template<bool QKV3, bool RESID>
__global__ __launch_bounds__(256, 2)
void gemm3(const unsigned short* __restrict__ Ah, const unsigned short* __restrict__ Al,
           const unsigned short* __restrict__ Bp,
           const float* __restrict__ b0, const float* __restrict__ b1,
           const float* __restrict__ b2,
           const float* __restrict__ resid, float* __restrict__ C,
           int N, int K)
{
    __shared__ __attribute__((aligned(16))) unsigned short Ahs[4 * 128 * 8];
    __shared__ __attribute__((aligned(16))) unsigned short Als[4 * 128 * 8];
    __shared__ __attribute__((aligned(16))) unsigned short Bhs[4 * 128 * 8];
    __shared__ __attribute__((aligned(16))) unsigned short Bls[4 * 128 * 8];

    const int z  = QKV3 ? blockIdx.z : 0;
    const int m0 = blockIdx.y * 128;
    const int n0 = blockIdx.x * 128;
    const size_t plane = (size_t)(K / 8) * N * 8;
    const unsigned short* Bh = Bp + (size_t)z * 2 * plane;
    const unsigned short* Bl = Bh + plane;
    const float* bp = QKV3 ? (z == 0 ? b0 : z == 1 ? b1 : b2) : b0;
    float* Cp = C + (QKV3 ? (size_t)z * NT * N : 0);

    const int tid  = threadIdx.x;
    const int lane = tid & 63, wid = tid >> 6;
    const int quad = lane >> 4, l16 = lane & 15;
    const int wm = (wid >> 1) * 64;
    const int wn = (wid & 1) * 64;

    // staging: chunk c = q*128 + idx (16B per chunk), 512 chunks/plane, 2/thread
    const unsigned short *gAh[2], *gAl[2], *gBh[2], *gBl[2];
    void *lAh[2], *lAl[2], *lBh[2], *lBl[2];
    #pragma unroll
    for (int i = 0; i < 2; ++i) {
        const int c = tid + 256 * i;
        const int q = c >> 7, idx = c & 127;
        gAh[i] = Ah + (size_t)(m0 + idx) * K + q * 8;
        gAl[i] = Al + (size_t)(m0 + idx) * K + q * 8;
        gBh[i] = Bh + ((size_t)q * N + n0 + idx) * 8;
        gBl[i] = Bl + ((size_t)q * N + n0 + idx) * 8;
        lAh[i] = (void*)&Ahs[(size_t)c * 8];
        lAl[i] = (void*)&Als[(size_t)c * 8];
        lBh[i] = (void*)&Bhs[(size_t)c * 8];
        lBl[i] = (void*)&Bls[(size_t)c * 8];
    }

    f32x4 acc[4][4];
    #pragma unroll
    for (int mi = 0; mi < 4; ++mi)
        #pragma unroll
        for (int ni = 0; ni < 4; ++ni)
            acc[mi][ni] = (f32x4){0.f, 0.f, 0.f, 0.f};

    const size_t bstep = (size_t)4 * N * 8;
    for (int ks = 0; ks < K / 32; ++ks) {
        __syncthreads();
        #pragma unroll
        for (int i = 0; i < 2; ++i) {
            gload_lds16(gAh[i], lAh[i]);
            gload_lds16(gAl[i], lAl[i]);
            gload_lds16(gBh[i], lBh[i]);
            gload_lds16(gBl[i], lBl[i]);
            gAh[i] += 32; gAl[i] += 32; gBh[i] += bstep; gBl[i] += bstep;
        }
        __syncthreads();

        bf16x8 ah[4], al[4], bh[4], bl[4];
        #pragma unroll
        for (int mi = 0; mi < 4; ++mi) {
            ah[mi] = *(const bf16x8*)&Ahs[((size_t)quad * 128 + wm + mi * 16 + l16) * 8];
            al[mi] = *(const bf16x8*)&Als[((size_t)quad * 128 + wm + mi * 16 + l16) * 8];
        }
        #pragma unroll
        for (int ni = 0; ni < 4; ++ni) {
            bh[ni] = *(const bf16x8*)&Bhs[((size_t)quad * 128 + wn + ni * 16 + l16) * 8];
            bl[ni] = *(const bf16x8*)&Bls[((size_t)quad * 128 + wn + ni * 16 + l16) * 8];
        }
        #pragma unroll
        for (int mi = 0; mi < 4; ++mi)
            #pragma unroll
            for (int ni = 0; ni < 4; ++ni) {
                acc[mi][ni] = __builtin_amdgcn_mfma_f32_16x16x32_bf16(
                    ah[mi], bh[ni], acc[mi][ni], 0, 0, 0);
                acc[mi][ni] = __builtin_amdgcn_mfma_f32_16x16x32_bf16(
                    ah[mi], bl[ni], acc[mi][ni], 0, 0, 0);
                acc[mi][ni] = __builtin_amdgcn_mfma_f32_16x16x32_bf16(
                    al[mi], bh[ni], acc[mi][ni], 0, 0, 0);
            }
    }

    // epilogue: C/D layout col=l16, row=quad*4+reg
    #pragma unroll
    for (int mi = 0; mi < 4; ++mi) {
        const int rbase = wm + mi * 16 + quad * 4;
        #pragma unroll
        for (int r = 0; r < 4; ++r) {
            const size_t gm = m0 + rbase + r;
            #pragma unroll
            for (int ni = 0; ni < 4; ++ni) {
                const int col = n0 + wn + ni * 16 + l16;
                float vv = acc[mi][ni][r] + bp[col];
                if (RESID) vv += resid[gm * N + col];
                Cp[gm * N + col] = vv;
            }
        }
    }
}

// ---------------- MFMA flash attention (bf16x3 split precision) -------------
// Block: 128 q-rows, 4 waves x 32 q. Per kv-tile (64 rows):
//   S^T = K·Q^T via mfma_32x32x16 (3 passes Kh·Qh + Kh·Ql + Kl·Qh)
//   -> lane-local online softmax (q = lane&31)
//   -> P hi/lo frags built in-register (cross-half shfl_xor exchange)
//   -> O^T += V^T·P (3 passes Vh·Ph + Vh·Pl + Vl·Ph)
// K LDS: [doct][row][8] pad-520; V LDS: transposed [d][j] with octet XOR
// swizzle (j>>3)^(d&7) so PV ds_read_b128 avoids stride-128B conflicts.
// T14: next tile's K/V global loads issued before compute, written next iter.
__global__ __launch_bounds__(256, 2)
void attn_kernel(const float* __restrict__ q, const float* __restrict__ k,
                 const float* __restrict__ v,
                 unsigned short* __restrict__ oh, unsigned short* __restrict__ ol)
{
    struct KV {
        unsigned short Kp[2][4160];   // [plane][doct*520 + row*8 + (d&7)]
        unsigned short Vp[2][4096];   // [plane][d*64 + ((j>>3)^(d&7))*8 + (j&7)]
    };
    __shared__ union SMem { KV kv; float O[4 * 64 * 33]; } sm;
    __shared__ float linv[128];

    const int qt = blockIdx.x, hh = blockIdx.y, b = blockIdx.z;
    const int tid = threadIdx.x;
    const int lane = tid & 63, w = tid >> 6;
    const int l31 = lane & 31, hf = lane >> 5;

    const size_t rowbase = (size_t)b * NS;
    const size_t cb = (size_t)hh * HD;

    // ---- issue tile-0 K/V loads ------------------------------------------
    float4 kreg[4], vreg[2][2];
    auto loadKV = [&](int kt) {
        #pragma unroll
        for (int i = 0; i < 4; ++i) {
            const int c = tid + 256 * i, j = c >> 4, d4 = (c & 15) << 2;
            kreg[i] = *(const float4*)(k + (rowbase + kt * 64 + j) * NHID + cb + d4);
        }
        #pragma unroll
        for (int i = 0; i < 2; ++i) {
            const int c = tid + 256 * i;
            const int j2 = ((c >> 6) << 3) + (((c >> 4) & 3) << 1);
            const int d4 = (c & 15) << 2;
            vreg[i][0] = *(const float4*)(v + (rowbase + kt * 64 + j2) * NHID + cb + d4);
            vreg[i][1] = *(const float4*)(v + (rowbase + kt * 64 + j2 + 1) * NHID + cb + d4);
        }
    };
    loadKV(0);

    // ---- Q fragments in registers (hi/lo), 1/sqrt(D) folded ---------------
    // B-operand layout: lane holds Q[qb + l31][16s + 8hf + e]
    bf16x8 qfh[4], qfl[4];
    {
        const int qrow = qt * 128 + w * 32 + l31;
        const float* qp = q + (rowbase + qrow) * NHID + cb + hf * 8;
        #pragma unroll
        for (int s = 0; s < 4; ++s) {
            const float4 f0 = *(const float4*)(qp + s * 16);
            const float4 f1 = *(const float4*)(qp + s * 16 + 4);
            const float ff[8] = {f0.x, f0.y, f0.z, f0.w, f1.x, f1.y, f1.z, f1.w};
            #pragma unroll
            for (int e = 0; e < 8; ++e) {
                const float sv = ff[e] * 0.125f;
                const unsigned short hv = f2bf(sv);
                qfh[s][e] = (short)hv;
                qfl[s][e] = (short)f2bf(sv - bf2f(hv));
            }
        }
    }

    f32x16 oa[2];
    #pragma unroll
    for (int mfd = 0; mfd < 2; ++mfd)
        #pragma unroll
        for (int r = 0; r < 16; ++r) oa[mfd][r] = 0.f;
    float m_run = -1e30f, l_run = 0.f;

    for (int kt = 0; kt < NS / 64; ++kt) {
        __syncthreads();   // previous tile's LDS reads done

        // ---- write staged K (hi/lo, gemm layout, pad 520) -----------------
        #pragma unroll
        for (int i = 0; i < 4; ++i) {
            const int c = tid + 256 * i, j = c >> 4, d4 = (c & 15) << 2;
            const float* f = (const float*)&kreg[i];
            unsigned short hs[4], ls[4];
            #pragma unroll
            for (int e = 0; e < 4; ++e) {
                hs[e] = f2bf(f[e]); ls[e] = f2bf(f[e] - bf2f(hs[e]));
            }
            u32x2 wh, wl;
            wh[0] = hs[0] | ((unsigned)hs[1] << 16); wh[1] = hs[2] | ((unsigned)hs[3] << 16);
            wl[0] = ls[0] | ((unsigned)ls[1] << 16); wl[1] = ls[2] | ((unsigned)ls[3] << 16);
            const int ad = (d4 >> 3) * 520 + j * 8 + (d4 & 7);
            *(u32x2*)&sm.kv.Kp[0][ad] = wh;
            *(u32x2*)&sm.kv.Kp[1][ad] = wl;
        }
        // ---- write staged V (transposed + octet swizzle, hi/lo) -----------
        #pragma unroll
        for (int i = 0; i < 2; ++i) {
            const int c = tid + 256 * i;
            const int j2 = ((c >> 6) << 3) + (((c >> 4) & 3) << 1);
            const int d4 = (c & 15) << 2;
            const float* fa = (const float*)&vreg[i][0];
            const float* fb = (const float*)&vreg[i][1];
            #pragma unroll
            for (int dd = 0; dd < 4; ++dd) {
                const int d = d4 + dd;
                const unsigned short ah_ = f2bf(fa[dd]), bh_ = f2bf(fb[dd]);
                const unsigned short al_ = f2bf(fa[dd] - bf2f(ah_));
                const unsigned short bl_ = f2bf(fb[dd] - bf2f(bh_));
                const int ad = d * 64 + (((j2 >> 3) ^ (d & 7)) << 3) + (j2 & 7);
                *(unsigned*)&sm.kv.Vp[0][ad] = ah_ | ((unsigned)bh_ << 16);
                *(unsigned*)&sm.kv.Vp[1][ad] = al_ | ((unsigned)bl_ << 16);
            }
        }
        if (kt + 1 < NS / 64) loadKV(kt + 1);   // T14: hide HBM under compute
        __syncthreads();   // LDS ready

        // ---- S^T = K·Q^T, 3 passes ---------------------------------------
        f32x16 sa[2];
        #pragma unroll
        for (int mf = 0; mf < 2; ++mf)
            #pragma unroll
            for (int r = 0; r < 16; ++r) sa[mf][r] = 0.f;
        #pragma unroll
        for (int mf = 0; mf < 2; ++mf) {
            bf16x8 kf[4];
            #pragma unroll
            for (int s = 0; s < 4; ++s)
                kf[s] = *(const bf16x8*)&sm.kv.Kp[0][(2*s+hf)*520 + (mf*32+l31)*8];
            #pragma unroll
            for (int s = 0; s < 4; ++s)
                sa[mf] = __builtin_amdgcn_mfma_f32_32x32x16_bf16(kf[s], qfh[s], sa[mf], 0, 0, 0);
            #pragma unroll
            for (int s = 0; s < 4; ++s)
                sa[mf] = __builtin_amdgcn_mfma_f32_32x32x16_bf16(kf[s], qfl[s], sa[mf], 0, 0, 0);
            #pragma unroll
            for (int s = 0; s < 4; ++s)
                kf[s] = *(const bf16x8*)&sm.kv.Kp[1][(2*s+hf)*520 + (mf*32+l31)*8];
            #pragma unroll
            for (int s = 0; s < 4; ++s)
                sa[mf] = __builtin_amdgcn_mfma_f32_32x32x16_bf16(kf[s], qfh[s], sa[mf], 0, 0, 0);
        }

        // ---- online softmax: lane owns row q = qb + l31 -------------------
        float tm = sa[0][0];
        #pragma unroll
        for (int r = 1; r < 16; ++r) tm = fmaxf(tm, sa[0][r]);
        #pragma unroll
        for (int r = 0; r < 16; ++r) tm = fmaxf(tm, sa[1][r]);
        tm = fmaxf(tm, __shfl_xor(tm, 32));
        const float newm = fmaxf(m_run, tm);
        const float al = __expf(m_run - newm);
        m_run = newm;
        float ps = 0.f;
        #pragma unroll
        for (int mf = 0; mf < 2; ++mf)
            #pragma unroll
            for (int r = 0; r < 16; ++r) {
                const float pv = __expf(sa[mf][r] - newm);
                sa[mf][r] = pv; ps += pv;
            }
        ps += __shfl_xor(ps, 32);
        l_run = l_run * al + ps;
        #pragma unroll
        for (int mfd = 0; mfd < 2; ++mfd)
            #pragma unroll
            for (int r = 0; r < 16; ++r) oa[mfd][r] *= al;

        // ---- P fragments (hi/lo) via cross-half exchange ------------------
        // frag for j-step t: lane element e <-> j = 16t + 8hf + e
        bf16x8 pfh[4], pfl[4];
        #pragma unroll
        for (int t = 0; t < 4; ++t) {
            const int mfp = t >> 1, u8 = (t & 1) * 8;
            unsigned short hb[8]; float lo8[8];
            #pragma unroll
            for (int e = 0; e < 8; ++e) {
                const float pv = sa[mfp][u8 + e];
                hb[e] = f2bf(pv); lo8[e] = pv - bf2f(hb[e]);
            }
            {
                const unsigned X0 = hb[0] | ((unsigned)hb[1] << 16);
                const unsigned X1 = hb[2] | ((unsigned)hb[3] << 16);
                const unsigned X2 = hb[4] | ((unsigned)hb[5] << 16);
                const unsigned X3 = hb[6] | ((unsigned)hb[7] << 16);
                const unsigned s0 = (unsigned)__shfl_xor((int)X0, 32);
                const unsigned s1 = (unsigned)__shfl_xor((int)X1, 32);
                const unsigned s2 = (unsigned)__shfl_xor((int)X2, 32);
                const unsigned s3 = (unsigned)__shfl_xor((int)X3, 32);
                union UU { unsigned wd[4]; bf16x8 vv; } uu;
                uu.wd[0] = hf ? s2 : X0;
                uu.wd[1] = hf ? s3 : X1;
                uu.wd[2] = hf ? X2 : s0;
                uu.wd[3] = hf ? X3 : s1;
                pfh[t] = uu.vv;
            }
            {
                unsigned short lb[8];
                #pragma unroll
                for (int e = 0; e < 8; ++e) lb[e] = f2bf(lo8[e]);
                const unsigned Y0 = lb[0] | ((unsigned)lb[1] << 16);
                const unsigned Y1 = lb[2] | ((unsigned)lb[3] << 16);
                const unsigned Y2 = lb[4] | ((unsigned)lb[5] << 16);
                const unsigned Y3 = lb[6] | ((unsigned)lb[7] << 16);
                const unsigned s0 = (unsigned)__shfl_xor((int)Y0, 32);
                const unsigned s1 = (unsigned)__shfl_xor((int)Y1, 32);
                const unsigned s2 = (unsigned)__shfl_xor((int)Y2, 32);
                const unsigned s3 = (unsigned)__shfl_xor((int)Y3, 32);
                union UU { unsigned wd[4]; bf16x8 vv; } uu;
                uu.wd[0] = hf ? s2 : Y0;
                uu.wd[1] = hf ? s3 : Y1;
                uu.wd[2] = hf ? Y2 : s0;
                uu.wd[3] = hf ? Y3 : s1;
                pfl[t] = uu.vv;
            }
        }

        // ---- O^T += V^T·P, 3 passes --------------------------------------
        #pragma unroll
        for (int mfd = 0; mfd < 2; ++mfd) {
            const int db = (mfd * 32 + l31) * 64;
            const int sw = l31 & 7;           // d&7 for this lane
            bf16x8 vf[4];
            #pragma unroll
            for (int ks = 0; ks < 4; ++ks)
                vf[ks] = *(const bf16x8*)&sm.kv.Vp[0][db + (((2*ks+hf) ^ sw) << 3)];
            #pragma unroll
            for (int ks = 0; ks < 4; ++ks)
                oa[mfd] = __builtin_amdgcn_mfma_f32_32x32x16_bf16(vf[ks], pfh[ks], oa[mfd], 0, 0, 0);
            #pragma unroll
            for (int ks = 0; ks < 4; ++ks)
                oa[mfd] = __builtin_amdgcn_mfma_f32_32x32x16_bf16(vf[ks], pfl[ks], oa[mfd], 0, 0, 0);
            #pragma unroll
            for (int ks = 0; ks < 4; ++ks)
                vf[ks] = *(const bf16x8*)&sm.kv.Vp[1][db + (((2*ks+hf) ^ sw) << 3)];
            #pragma unroll
            for (int ks = 0; ks < 4; ++ks)
                oa[mfd] = __builtin_amdgcn_mfma_f32_32x32x16_bf16(vf[ks], pfh[ks], oa[mfd], 0, 0, 0);
        }
    }

    // ---- epilogue: O^T -> padded LDS -> normalized hi/lo bf16 stores ------
    __syncthreads();   // done reading K/V LDS; overlay with O
    {
        float* Ow = sm.O + w * (64 * 33);
        #pragma unroll
        for (int mfd = 0; mfd < 2; ++mfd)
            #pragma unroll
            for (int r = 0; r < 16; ++r) {
                const int dr = mfd * 32 + (r & 3) + 8 * (r >> 2) + 4 * hf;
                Ow[dr * 33 + l31] = oa[mfd][r];
            }
        if (hf == 0) linv[w * 32 + l31] = 1.0f / l_run;
    }
    __syncthreads();
    #pragma unroll
    for (int it = 0; it < 8; ++it) {
        const int c = tid + 256 * it;
        const int qq = c >> 4, d4 = (c & 15) << 2;
        const float* Or = sm.O + (qq >> 5) * (64 * 33) + (qq & 31);
        const float sc_ = linv[qq];
        unsigned short hs[4], ls[4];
        #pragma unroll
        for (int e = 0; e < 4; ++e) {
            const float vv = Or[(d4 + e) * 33] * sc_;
            hs[e] = f2bf(vv); ls[e] = f2bf(vv - bf2f(hs[e]));
        }
        u32x2 ph_, pl_;
        ph_[0] = hs[0] | ((unsigned)hs[1] << 16); ph_[1] = hs[2] | ((unsigned)hs[3] << 16);
        pl_[0] = ls[0] | ((unsigned)ls[1] << 16); pl_[1] = ls[2] | ((unsigned)ls[3] << 16);
        const size_t o = (rowbase + qt * 128 + qq) * NHID + cb + d4;
        *(u32x2*)&oh[o] = ph_;
        *(u32x2*)&ol[o] = pl_;
    }
}

// ---------------- Gate: fp32 logits, argmax (first-max), token scatter ------
__global__ __launch_bounds__(64)
void gate_kernel(const float* __restrict__ hn2, const float* __restrict__ gw,
                 const float* __restrict__ gb, int* __restrict__ counts,
                 int* __restrict__ tok)
{
    const int t = blockIdx.x, lane = threadIdx.x;
    const float* row = hn2 + (size_t)t * NHID;
    float acc[NE] = {};
    for (int hh = lane; hh < NHID; hh += 64) {
        const float xv = row[hh];
        const float4 g0 = ((const float4*)(gw + (size_t)hh * NE))[0];
        const float4 g1 = ((const float4*)(gw + (size_t)hh * NE))[1];
        acc[0] += xv * g0.x; acc[1] += xv * g0.y; acc[2] += xv * g0.z; acc[3] += xv * g0.w;
        acc[4] += xv * g1.x; acc[5] += xv * g1.y; acc[6] += xv * g1.z; acc[7] += xv * g1.w;
    }
    #pragma unroll
    for (int e = 0; e < NE; ++e)
        for (int off = 32; off > 0; off >>= 1)
            acc[e] += __shfl_down(acc[e], off);
    if (lane == 0) {
        float best = -1e30f; int bi = 0;
        #pragma unroll
        for (int e = 0; e < NE; ++e) {
            const float lv = acc[e] + gb[e];
            if (lv > best) { best = lv; bi = e; }   // strict >: first-max (jnp.argmax)
        }
        const int pos = atomicAdd(&counts[bi], 1);
        tok[(size_t)bi * NT + pos] = t;
    }
}

// ---------------- MoE grouped GEMM, depth-2 counted-vmcnt pipeline (R6) -----
// Grid: 1D, id -> { e = id%8 (XCD pin), nb = (id/8)%nn, r0 = (id/8)/nn }.
// Per m-tile: 3 LDS buffers; prologue stages tiles 0,1; iter ks stages ks+2
// and waits s_waitcnt vmcnt(W) (W = gloads/tile) -- loads for tile ks+1 stay
// in flight across the barrier, so the k-chain no longer pays HBM latency.
// Safety: [wait][s_barrier][stage ks+2][ds_read ks][MFMA]; buffer (ks)%3 is
// rewritten only in iter ks+1, after the barrier that proves all waves
// finished reading it (their MFMAs consumed the ds_reads before arriving).
template<int BN, int MSPLIT, bool BF16OUT>
__global__ __launch_bounds__(256, 4)
void moe_gemm(const unsigned short* __restrict__ A,   // bf16 [NT][K]
              const unsigned short* __restrict__ Bp,  // bf16 packed [E][K/8][N][8]
              const float* __restrict__ bias,         // [E][N]
              const float* __restrict__ resid,        // [NT][N] or null
              void* __restrict__ Cout,                // bf16 or fp32 [NT][N]
              int N, int K,
              const int* __restrict__ rows, const int* __restrict__ counts)
{
    constexpr int NI = BN / 32;
    constexpr int NBCH = (4 * BN) / 256;   // B gloads/thread/tile (128->2, 64->1)
    constexpr int W = 2 + NBCH;            // gload instr per tile per wave
    __shared__ __attribute__((aligned(16))) unsigned short As[3][4 * 128 * 8];
    __shared__ __attribute__((aligned(16))) unsigned short Bs[3][4 * BN * 8];

    const int id = blockIdx.x;
    const int e  = id & 7;                 // expert -> XCD (round-robin dispatch)
    const int nn = N / BN;
    const int nb = (id >> 3) % nn;
    const int r0 = (id >> 3) / nn;
    const int n0 = nb * BN;

    const int Meff = counts[e];
    const int* rl = rows + (size_t)e * NT;
    const int nmt = (Meff + 127) >> 7;     // m-tiles for this expert

    const int tid  = threadIdx.x;
    const int lane = tid & 63, wid = tid >> 6;
    const int quad = lane >> 4, l16 = lane & 15;
    const int wm = (wid >> 1) * 64;
    const int wn = (wid & 1) * (BN / 2);
    const int NK = K / 32;
    const size_t bstep = (size_t)4 * N * 8;

    for (int mt = r0; mt < nmt; mt += MSPLIT) {
        const int m0 = mt * 128;
        __syncthreads();   // prev m-tile's readers done before restaging bufs

        const unsigned short* gA[2];
        #pragma unroll
        for (int i = 0; i < 2; ++i) {
            const int c = tid + 256 * i;
            const int q = c >> 7, row = c & 127;
            int m = m0 + row; if (m >= Meff) m = Meff - 1;
            gA[i] = A + (size_t)rl[m] * K + q * 8;
        }
        const unsigned short* gB[NBCH];
        #pragma unroll
        for (int i = 0; i < NBCH; ++i) {
            const int c = tid + 256 * i;
            const int q = c / BN, n = c % BN;
            gB[i] = Bp + (((size_t)e * (K / 8) + q) * N + n0 + n) * 8;
        }

        auto stage = [&](int b) {          // issues exactly W vmem instrs/wave
            gload_lds16(gA[0], (void*)&As[b][(size_t)tid * 8]);
            gload_lds16(gA[1], (void*)&As[b][(size_t)(tid + 256) * 8]);
            #pragma unroll
            for (int i = 0; i < NBCH; ++i)
                gload_lds16(gB[i], (void*)&Bs[b][(size_t)(tid + 256 * i) * 8]);
            gA[0] += 32; gA[1] += 32;
            #pragma unroll
            for (int i = 0; i < NBCH; ++i) gB[i] += bstep;
        };

        f32x4 acc[4][NI];
        #pragma unroll
        for (int mi = 0; mi < 4; ++mi)
            #pragma unroll
            for (int ni = 0; ni < NI; ++ni)
                acc[mi][ni] = (f32x4){0.f, 0.f, 0.f, 0.f};

        stage(0);                          // tiles 0,1 in flight (2W outstanding)
        stage(1);

        int cur = 0;
        for (int ks = 0; ks < NK; ++ks) {
            if (ks < NK - 1)               // tile ks done; ks+1 stays in flight
                asm volatile("s_waitcnt vmcnt(%0)" :: "n"(W) : "memory");
            else                           // last tile: drain
                asm volatile("s_waitcnt vmcnt(0)" ::: "memory");
            __builtin_amdgcn_s_barrier();
            asm volatile("" ::: "memory");

            if (ks + 2 < NK) {
                const int nx = cur >= 1 ? cur - 1 : cur + 2;   // (cur+2)%3
                stage(nx);
            }

            bf16x8 af[4], bfr[NI];
            #pragma unroll
            for (int mi = 0; mi < 4; ++mi)
                af[mi] = *(const bf16x8*)&As[cur][((size_t)quad * 128 + wm + mi * 16 + l16) * 8];
            #pragma unroll
            for (int ni = 0; ni < NI; ++ni)
                bfr[ni] = *(const bf16x8*)&Bs[cur][((size_t)quad * BN + wn + ni * 16 + l16) * 8];
            #pragma unroll
            for (int mi = 0; mi < 4; ++mi)
                #pragma unroll
                for (int ni = 0; ni < NI; ++ni)
                    acc[mi][ni] = __builtin_amdgcn_mfma_f32_16x16x32_bf16(
                        af[mi], bfr[ni], acc[mi][ni], 0, 0, 0);

            cur = cur == 2 ? 0 : cur + 1;
        }

        #pragma unroll
        for (int mi = 0; mi < 4; ++mi) {
            const int rbase = wm + mi * 16 + quad * 4;
            #pragma unroll
            for (int r = 0; r < 4; ++r) {
                const int m = m0 + rbase + r;
                if (m >= Meff) continue;
                const int gr = rl[m];
                #pragma unroll
                for (int ni = 0; ni < NI; ++ni) {
                    const int col = n0 + wn + ni * 16 + l16;
                    float vv = acc[mi][ni][r] + bias[(size_t)e * N + col];
                    if (BF16OUT) {
                        vv = fmaxf(vv, 0.f);
                        ((unsigned short*)Cout)[(size_t)gr * N + col] = f2bf(vv);
                    } else {
                        vv += resid[(size_t)gr * N + col];
                        ((float*)Cout)[(size_t)gr * N + col] = vv;
                    }
                }
            }
        }
    }
}

// ---------------------------------------------------------------------------
extern "C" void kernel_launch(void* const* d_in, const int* in_sizes, int n_in,
                              void* d_out, int out_size, void* d_ws, size_t ws_size,
                              hipStream_t stream)
{
    (void)in_sizes; (void)n_in; (void)out_size; (void)ws_size;
    const float* x      = (const float*)d_in[0];
    const float* ln1_g  = (const float*)d_in[1];
    const float* ln1_b  = (const float*)d_in[2];
    const float* ln2_g  = (const float*)d_in[3];
    const float* ln2_b  = (const float*)d_in[4];
    const float* wq     = (const float*)d_in[5];
    const float* bq     = (const float*)d_in[6];
    const float* wk     = (const float*)d_in[7];
    const float* bk     = (const float*)d_in[8];
    const float* wv     = (const float*)d_in[9];
    const float* bv     = (const float*)d_in[10];
    const float* wo     = (const float*)d_in[11];
    const float* bo     = (const float*)d_in[12];
    const float* gate_w = (const float*)d_in[13];
    const float* gate_b = (const float*)d_in[14];
    const float* w1     = (const float*)d_in[15];
    const float* b1     = (const float*)d_in[16];
    const float* w2     = (const float*)d_in[17];
    const float* b2     = (const float*)d_in[18];
    float* out = (float*)d_out;

    // workspace layout (128 MiB total; R1 proved 128.13 MiB ok):
    //  0-16   q        -> (after Wo) MoE wpack [0,64)
    //  16-32  k
    //  32-48  v
    //  48-56  hnh      -> (after QKV) oh
    //  56-64  hnl      -> ol
    //  64-76  qkv weight packs (hi+lo, 4 MiB each) -> (after Wo) hn2bf 64-72
    //  72-76  (dead wv pack) -> tok (128 KB) + cnts
    //  76-80  wo pack
    //  80-96  x2 (alive to end)
    //  96-112 hn2f     -> (after gate) mid low half
    //  96-128 mid bf16 [NT][NF]
    char* W8 = (char*)d_ws;
    float*          qbuf   = (float*)(W8);
    float*          kbuf   = (float*)(W8 + 16 * MiB);
    float*          vbuf   = (float*)(W8 + 32 * MiB);
    unsigned short* hnh    = (unsigned short*)(W8 + 48 * MiB);
    unsigned short* hnl    = (unsigned short*)(W8 + 56 * MiB);
    unsigned short* ohb    = (unsigned short*)(W8 + 48 * MiB);
    unsigned short* olb    = (unsigned short*)(W8 + 56 * MiB);
    unsigned short* qkvpk  = (unsigned short*)(W8 + 64 * MiB);   // [3][2][128][1024][8]
    unsigned short* wopk   = (unsigned short*)(W8 + 76 * MiB);
    unsigned short* hn2bf  = (unsigned short*)(W8 + 64 * MiB);
    int*            tok    = (int*)(W8 + 72 * MiB);
    int*            cnts   = (int*)(W8 + 72 * MiB + (size_t)NE * NT * 4);
    float*          x2buf  = (float*)(W8 + 80 * MiB);
    float*          hn2f   = (float*)(W8 + 96 * MiB);
    unsigned short* mid    = (unsigned short*)(W8 + 96 * MiB);
    unsigned short* wpack  = (unsigned short*)(W8);              // MoE, 64 MiB

    const size_t wsz = (size_t)2 * NHID * NHID;   // elems per packed weight (hi+lo)

    // 0. pack QKV + Wo weights -> hi/lo bf16 planes
    {
        dim3 g(NHID / 256, NHID / 8, 1);
        pack_whl<<<g, 256, 0, stream>>>(wq, qkvpk,           NHID, NHID);
        pack_whl<<<g, 256, 0, stream>>>(wk, qkvpk + wsz,     NHID, NHID);
        pack_whl<<<g, 256, 0, stream>>>(wv, qkvpk + 2 * wsz, NHID, NHID);
        pack_whl<<<g, 256, 0, stream>>>(wo, wopk,            NHID, NHID);
    }

    // 1. LN1(x) -> hi/lo planes
    ln_kernel<0><<<NT, 256, 0, stream>>>(x, ln1_g, ln1_b, nullptr, hnh, hnl);

    // 2. q,k,v = hn @ {wq,wk,wv} + bias   (bf16x3 MFMA, fused over z)
    {
        dim3 g(NHID / 128, NT / 128, 3);
        gemm3<true, false><<<g, 256, 0, stream>>>(
            hnh, hnl, qkvpk, bq, bk, bv, nullptr, qbuf, NHID, NHID);
    }

    // 3. o = attention(q,k,v) -> hi/lo planes (overwrites hnh/hnl)
    {
        dim3 g(NS / 128, NHEAD, NB);
        attn_kernel<<<g, 256, 0, stream>>>(qbuf, kbuf, vbuf, ohb, olb);
    }

    // 4. x2 = x + o @ wo + bo   (bf16x3 MFMA)
    {
        dim3 g(NHID / 128, NT / 128, 1);
        gemm3<false, true><<<g, 256, 0, stream>>>(
            ohb, olb, wopk, bo, nullptr, nullptr, x, x2buf, NHID, NHID);
    }

    // 5. hn2 = LN2(x2) -> fp32 (gate) + bf16 hi (MoE A)
    ln_kernel<1><<<NT, 256, 0, stream>>>(x2buf, ln2_g, ln2_b, hn2f, hn2bf, nullptr);

    // 6. top-1 routing (fp32)
    hipMemsetAsync(cnts, 0, NE * sizeof(int), stream);
    gate_kernel<<<NT, 64, 0, stream>>>(hn2f, gate_w, gate_b, cnts, tok);

    // 7. pack w1 (hi only) -> wpack (overwrites q/k/v/oh/ol; all dead)
    {
        dim3 g(NF / 256, NHID / 8, NE);
        pack_w<<<g, 256, 0, stream>>>(w1, wpack, NHID, NF);
    }
    // 8. mid = relu(gather(hn2bf) @ w1[e] + b1[e])  (bf16 out; overlays hn2f)
    //    grid: 8 experts x 32 n-blocks x MSPLIT 3 = 768 blocks (3/CU, 48KB LDS)
    moe_gemm<128, 3, true><<<NE * (NF / 128) * 3, 256, 0, stream>>>(
        hn2bf, wpack, b1, nullptr, mid, NF, NHID, tok, cnts);
    // 9. pack w2 (GEMM1 done with w1 pack)
    {
        dim3 g(NHID / 256, NF / 8, NE);
        pack_w<<<g, 256, 0, stream>>>(w2, wpack, NF, NHID);
    }
    // 10. out = x2 + gather(mid) @ w2[e] + b2[e]
    //     grid: 8 experts x 16 n-blocks x MSPLIT 5 = 640 blocks (4/CU, 36KB LDS)
    moe_gemm<64, 5, false><<<NE * (NHID / 64) * 5, 256, 0, stream>>>(
        mid, wpack, b2, x2buf, out, NHID, NF, tok, cnts);
}